// Round 1
// baseline (234.471 us; speedup 1.0000x reference)
//
#include <hip/hip_runtime.h>

// Problem constants: B=2, T=1024, E=1024, H=16, D=64
#define BB 2
#define TT 1024
#define EE 1024
#define HH 16
#define DD 64

// ---------------------------------------------------------------------------
// Kernel A: per (b,h) compute S_xx[64][64] = sum_t x_t x_t^T and s_x = sum_t x_t
// grid (32, 8): bh, t-chunk of 128. block 256. Atomic accumulate.
// ---------------------------------------------------------------------------
__global__ __launch_bounds__(256) void kA(const float* __restrict__ x,
                                          float* __restrict__ Sxx,
                                          float* __restrict__ sx) {
  const int bh = blockIdx.x;
  const int b = bh >> 4, h = bh & 15;
  const int t0 = blockIdx.y * 128;
  const int r = threadIdx.x;
  __shared__ float Xs[128 * 64];  // 32 KB
  const float* xb = x + ((size_t)b * TT + t0) * EE + h * 64;
#pragma unroll
  for (int j = 0; j < 8; ++j) {
    int idx4 = j * 256 + r;
    int t = idx4 >> 4, c4 = idx4 & 15;
    *reinterpret_cast<float4*>(&Xs[t * 64 + c4 * 4]) =
        *reinterpret_cast<const float4*>(&xb[(size_t)t * EE + c4 * 4]);
  }
  __syncthreads();
  const int p0 = (r >> 4) * 4, q0 = (r & 15) * 4;
  float acc[4][4] = {};
  for (int t = 0; t < 128; ++t) {
    float4 pv = *reinterpret_cast<const float4*>(&Xs[t * 64 + p0]);
    float4 qv = *reinterpret_cast<const float4*>(&Xs[t * 64 + q0]);
    float pa[4] = {pv.x, pv.y, pv.z, pv.w};
    float qa[4] = {qv.x, qv.y, qv.z, qv.w};
#pragma unroll
    for (int i = 0; i < 4; ++i)
#pragma unroll
      for (int j = 0; j < 4; ++j) acc[i][j] += pa[i] * qa[j];
  }
  float* Sb = Sxx + bh * 4096;
#pragma unroll
  for (int i = 0; i < 4; ++i)
#pragma unroll
    for (int j = 0; j < 4; ++j)
      atomicAdd(&Sb[(p0 + i) * 64 + q0 + j], acc[i][j]);
  if (r < 64) {
    float s = 0.f;
    for (int t = 0; t < 128; ++t) s += Xs[t * 64 + r];
    atomicAdd(&sx[bh * 64 + r], s);
  }
}

// ---------------------------------------------------------------------------
// Kernel B1: per (b,h,i): scores = (Wq S Wk^T + bias terms)/8 -> softmax ->
//            M[i*64+p][d] = sum_q w[p][q] Wv[i][q][d], c = w @ bv
// grid 512 (bh*16+i), block 256.
// ---------------------------------------------------------------------------
__global__ __launch_bounds__(256) void kB1(const float* __restrict__ Sxx,
                                           const float* __restrict__ sx,
                                           const float* __restrict__ Wq,
                                           const float* __restrict__ bq,
                                           const float* __restrict__ Wk,
                                           const float* __restrict__ bk,
                                           const float* __restrict__ Wv,
                                           const float* __restrict__ bv,
                                           float* __restrict__ M,
                                           float* __restrict__ c) {
  const int blk = blockIdx.x;
  const int bh = blk >> 4, ih = blk & 15;
  const int r = threadIdx.x;
  __shared__ float Ss[64 * 65];   // S_xx, later scores/w
  __shared__ float Ws[64 * 65];   // Wq -> Wk -> Wv
  __shared__ float A1[64 * 65];   // Wq @ S_xx
  __shared__ float svec[64], qs[64], ks[64], bqv[64], bkv[64], bvv[64];

#pragma unroll
  for (int j = 0; j < 16; ++j) {
    int idx = j * 256 + r;
    int row = idx >> 6, col = idx & 63;
    Ss[row * 65 + col] = Sxx[bh * 4096 + idx];
    Ws[row * 65 + col] = Wq[ih * 4096 + idx];
  }
  if (r < 64) {
    svec[r] = sx[bh * 64 + r];
    bqv[r] = bq[ih * 64 + r];
    bkv[r] = bk[ih * 64 + r];
    bvv[r] = bv[ih * 64 + r];
  }
  __syncthreads();
  const int p0 = (r >> 4) * 4, q0 = (r & 15) * 4;
  // A1[p][q'] = sum_d Wq[p][d] * S[d][q']
  {
    float acc[4][4] = {};
    for (int d = 0; d < 64; ++d) {
      float wv[4], sv[4];
#pragma unroll
      for (int i = 0; i < 4; ++i) wv[i] = Ws[(p0 + i) * 65 + d];
#pragma unroll
      for (int j = 0; j < 4; ++j) sv[j] = Ss[d * 65 + q0 + j];
#pragma unroll
      for (int i = 0; i < 4; ++i)
#pragma unroll
        for (int j = 0; j < 4; ++j) acc[i][j] += wv[i] * sv[j];
    }
#pragma unroll
    for (int i = 0; i < 4; ++i)
#pragma unroll
      for (int j = 0; j < 4; ++j) A1[(p0 + i) * 65 + q0 + j] = acc[i][j];
  }
  if (r < 64) {  // qs = Wq @ s_x
    float s = 0.f;
    for (int d = 0; d < 64; ++d) s += Ws[r * 65 + d] * svec[d];
    qs[r] = s;
  }
  __syncthreads();
#pragma unroll
  for (int j = 0; j < 16; ++j) {
    int idx = j * 256 + r;
    int row = idx >> 6, col = idx & 63;
    Ws[row * 65 + col] = Wk[ih * 4096 + idx];
  }
  __syncthreads();
  if (r < 64) {  // ks = Wk @ s_x
    float s = 0.f;
    for (int d = 0; d < 64; ++d) s += Ws[r * 65 + d] * svec[d];
    ks[r] = s;
  }
  __syncthreads();
  // scores[p][q] = (A1[p][:] . Wk[q][:] + qs[p]*bk[q] + bq[p]*ks[q] + T*bq[p]*bk[q]) / 8
  {
    float acc[4][4] = {};
    for (int d = 0; d < 64; ++d) {
      float av[4], kv[4];
#pragma unroll
      for (int i = 0; i < 4; ++i) av[i] = A1[(p0 + i) * 65 + d];
#pragma unroll
      for (int j = 0; j < 4; ++j) kv[j] = Ws[(q0 + j) * 65 + d];
#pragma unroll
      for (int i = 0; i < 4; ++i)
#pragma unroll
        for (int j = 0; j < 4; ++j) acc[i][j] += av[i] * kv[j];
    }
#pragma unroll
    for (int i = 0; i < 4; ++i)
#pragma unroll
      for (int j = 0; j < 4; ++j) {
        float v = acc[i][j] + qs[p0 + i] * bkv[q0 + j] + bqv[p0 + i] * ks[q0 + j] +
                  1024.f * bqv[p0 + i] * bkv[q0 + j];
        Ss[(p0 + i) * 65 + q0 + j] = v * 0.125f;
      }
  }
  __syncthreads();
  if (r < 64) {  // softmax over the row
    float* row = &Ss[r * 65];
    float m = row[0];
    for (int q = 1; q < 64; ++q) m = fmaxf(m, row[q]);
    float s = 0.f;
    for (int q = 0; q < 64; ++q) {
      float e = __expf(row[q] - m);
      row[q] = e;
      s += e;
    }
    float inv = 1.f / s;
    for (int q = 0; q < 64; ++q) row[q] *= inv;
  }
  __syncthreads();
#pragma unroll
  for (int j = 0; j < 16; ++j) {
    int idx = j * 256 + r;
    int row = idx >> 6, col = idx & 63;
    Ws[row * 65 + col] = Wv[ih * 4096 + idx];
  }
  __syncthreads();
  // M[p][d] = sum_q w[p][q] * Wv[q][d]
  {
    const int d0 = q0;
    float acc[4][4] = {};
    for (int q = 0; q < 64; ++q) {
      float wv[4], vv[4];
#pragma unroll
      for (int i = 0; i < 4; ++i) wv[i] = Ss[(p0 + i) * 65 + q];
#pragma unroll
      for (int j = 0; j < 4; ++j) vv[j] = Ws[q * 65 + d0 + j];
#pragma unroll
      for (int i = 0; i < 4; ++i)
#pragma unroll
        for (int j = 0; j < 4; ++j) acc[i][j] += wv[i] * vv[j];
    }
    float* Mb = M + (size_t)bh * 65536 + (size_t)(ih * 64) * 64;
#pragma unroll
    for (int i = 0; i < 4; ++i) {
      float4 v = make_float4(acc[i][0], acc[i][1], acc[i][2], acc[i][3]);
      *reinterpret_cast<float4*>(&Mb[(p0 + i) * 64 + d0]) = v;
    }
  }
  if (r < 64) {
    float s = 0.f;
    for (int q = 0; q < 64; ++q) s += Ss[r * 65 + q] * bvv[q];
    c[bh * 1024 + ih * 64 + r] = s;
  }
}

// ---------------------------------------------------------------------------
// Kernel B2: G[bh][f][d] = sum_e Wf[f][e] M[bh][e][d];  g = Wf @ c + bf
// grid (32, 16): bh, f-tile of 64. block 256.
// ---------------------------------------------------------------------------
__global__ __launch_bounds__(256) void kB2(const float* __restrict__ Wf,
                                           const float* __restrict__ bf,
                                           const float* __restrict__ M,
                                           const float* __restrict__ c,
                                           float* __restrict__ G,
                                           float* __restrict__ g) {
  const int bh = blockIdx.x;
  const int f0 = blockIdx.y * 64;
  const int r = threadIdx.x;
  __shared__ float Wfs[64 * 65];
  __shared__ float Ms[64 * 65];
  __shared__ float cs[64];
  const int fi0 = (r >> 4) * 4, d0 = (r & 15) * 4;
  float acc[4][4] = {};
  float gacc = 0.f;
  for (int e0 = 0; e0 < 1024; e0 += 64) {
#pragma unroll
    for (int j = 0; j < 16; ++j) {
      int idx = j * 256 + r;
      int row = idx >> 6, col = idx & 63;
      Wfs[row * 65 + col] = Wf[(size_t)(f0 + row) * EE + e0 + col];
      Ms[row * 65 + col] = M[(size_t)bh * 65536 + (size_t)(e0 + row) * 64 + col];
    }
    if (r < 64) cs[r] = c[bh * 1024 + e0 + r];
    __syncthreads();
    for (int e = 0; e < 64; ++e) {
      float fv[4], mv[4];
#pragma unroll
      for (int i = 0; i < 4; ++i) fv[i] = Wfs[(fi0 + i) * 65 + e];
#pragma unroll
      for (int j = 0; j < 4; ++j) mv[j] = Ms[e * 65 + d0 + j];
#pragma unroll
      for (int i = 0; i < 4; ++i)
#pragma unroll
        for (int j = 0; j < 4; ++j) acc[i][j] += fv[i] * mv[j];
    }
    if (r < 64) {
      float s = 0.f;
      for (int e = 0; e < 64; ++e) s += Wfs[r * 65 + e] * cs[e];
      gacc += s;
    }
    __syncthreads();
  }
  float* Gb = G + (size_t)bh * 65536;
#pragma unroll
  for (int i = 0; i < 4; ++i) {
    float4 v = make_float4(acc[i][0], acc[i][1], acc[i][2], acc[i][3]);
    *reinterpret_cast<float4*>(&Gb[(size_t)(f0 + fi0 + i) * 64 + d0]) = v;
  }
  if (r < 64) g[bh * 1024 + f0 + r] = gacc + bf[f0 + r];
}

// ---------------------------------------------------------------------------
// Kernel C: out[bh][t][f] = sum_d xh[bh][t][d] * G[bh][f][d] + g[bh][f]
// grid (32, 256): bh, (t-tile 16 x f-tile 16) of 64x64. block 256.
// ---------------------------------------------------------------------------
__global__ __launch_bounds__(256) void kC(const float* __restrict__ x,
                                          const float* __restrict__ G,
                                          const float* __restrict__ g,
                                          float* __restrict__ out) {
  const int bh = blockIdx.x;
  const int b = bh >> 4, h = bh & 15;
  const int tile = blockIdx.y;
  const int tt0 = (tile >> 4) * 64, ff0 = (tile & 15) * 64;
  const int r = threadIdx.x;
  __shared__ float Xs[64 * 65];
  __shared__ float Gs[64 * 65];
  __shared__ float gs[64];
#pragma unroll
  for (int j = 0; j < 16; ++j) {
    int idx = j * 256 + r;
    int row = idx >> 6, col = idx & 63;
    Xs[row * 65 + col] = x[((size_t)b * TT + tt0 + row) * EE + h * 64 + col];
    Gs[row * 65 + col] = G[(size_t)bh * 65536 + (size_t)(ff0 + row) * 64 + col];
  }
  if (r < 64) gs[r] = g[bh * 1024 + ff0 + r];
  __syncthreads();
  const int t0i = (r >> 4) * 4, f0i = (r & 15) * 4;
  float acc[4][4] = {};
  for (int d = 0; d < 64; ++d) {
    float xv[4], gv[4];
#pragma unroll
    for (int i = 0; i < 4; ++i) xv[i] = Xs[(t0i + i) * 65 + d];
#pragma unroll
    for (int j = 0; j < 4; ++j) gv[j] = Gs[(f0i + j) * 65 + d];
#pragma unroll
    for (int i = 0; i < 4; ++i)
#pragma unroll
      for (int j = 0; j < 4; ++j) acc[i][j] += xv[i] * gv[j];
  }
#pragma unroll
  for (int i = 0; i < 4; ++i) {
    float4 v = make_float4(acc[i][0] + gs[f0i + 0], acc[i][1] + gs[f0i + 1],
                           acc[i][2] + gs[f0i + 2], acc[i][3] + gs[f0i + 3]);
    size_t t = tt0 + t0i + i;
    *reinterpret_cast<float4*>(&out[((size_t)bh * TT + t) * EE + ff0 + f0i]) = v;
  }
}

extern "C" void kernel_launch(void* const* d_in, const int* in_sizes, int n_in,
                              void* d_out, int out_size, void* d_ws, size_t ws_size,
                              hipStream_t stream) {
  const float* x = (const float*)d_in[0];
  const float* Wq = (const float*)d_in[1];
  const float* bq = (const float*)d_in[2];
  const float* Wk = (const float*)d_in[3];
  const float* bk = (const float*)d_in[4];
  const float* Wv = (const float*)d_in[5];
  const float* bv = (const float*)d_in[6];
  const float* Wf = (const float*)d_in[7];
  const float* bf = (const float*)d_in[8];
  float* out = (float*)d_out;

  float* ws = (float*)d_ws;
  float* Sxx = ws;                     // 32*4096   = 131072 floats
  float* sx = Sxx + 32 * 4096;         // 32*64     = 2048
  float* M = sx + 32 * 64;             // 32*1024*64 = 2097152
  float* c = M + 32 * 1024 * 64;       // 32*1024   = 32768
  float* G = c + 32 * 1024;            // 32*1024*64 = 2097152
  float* g = G + 32 * 1024 * 64;       // 32*1024   = 32768

  hipMemsetAsync(Sxx, 0, (32 * 4096 + 32 * 64) * sizeof(float), stream);
  kA<<<dim3(32, 8), 256, 0, stream>>>(x, Sxx, sx);
  kB1<<<512, 256, 0, stream>>>(Sxx, sx, Wq, bq, Wk, bk, Wv, bv, M, c);
  kB2<<<dim3(32, 16), 256, 0, stream>>>(Wf, bf, M, c, G, g);
  kC<<<dim3(32, 256), 256, 0, stream>>>(x, G, g, out);
}

// Round 2
// 138.324 us; speedup vs baseline: 1.6951x; 1.6951x over previous
//
#include <hip/hip_runtime.h>

// Problem constants: B=2, T=1024, E=1024, H=16, D=64
#define BB 2
#define TT 1024
#define EE 1024
#define HH 16
#define DD 64

typedef __attribute__((ext_vector_type(8))) short short8;      // 8 bf16 (4 VGPR) MFMA frag
typedef __attribute__((ext_vector_type(4))) float floatx4;     // MFMA acc
typedef __attribute__((ext_vector_type(4))) unsigned short ushort4v;
typedef __attribute__((ext_vector_type(8))) unsigned short ushort8v;

static __device__ __forceinline__ unsigned short f2bf(float f) {
  union { float f; unsigned int u; } v; v.f = f;
  unsigned int u = v.u;
  u += 0x7FFFu + ((u >> 16) & 1u);  // RNE
  return (unsigned short)(u >> 16);
}

// ---------------------------------------------------------------------------
// kW: Wf (fp32 1024x1024) -> Wfbf (bf16, same layout)
// ---------------------------------------------------------------------------
__global__ __launch_bounds__(256) void kW(const float* __restrict__ Wf,
                                          unsigned short* __restrict__ Wfbf) {
  int idx = (blockIdx.x * 256 + threadIdx.x) * 4;
  float4 v = *reinterpret_cast<const float4*>(&Wf[idx]);
  ushort4v o;
  o[0] = f2bf(v.x); o[1] = f2bf(v.y); o[2] = f2bf(v.z); o[3] = f2bf(v.w);
  *reinterpret_cast<ushort4v*>(&Wfbf[idx]) = o;
}

// ---------------------------------------------------------------------------
// Kernel A: per (b,h): S_xx = sum_t x_t x_t^T, s_x = sum_t x_t (atomic accum)
//           + emit xbf[bh][t][d] (bf16) for kC.
// grid (32, 8): bh, t-chunk of 128. block 256.
// ---------------------------------------------------------------------------
__global__ __launch_bounds__(256) void kA(const float* __restrict__ x,
                                          float* __restrict__ Sxx,
                                          float* __restrict__ sx,
                                          unsigned short* __restrict__ xbf) {
  const int bh = blockIdx.x;
  const int b = bh >> 4, h = bh & 15;
  const int t0 = blockIdx.y * 128;
  const int r = threadIdx.x;
  __shared__ float Xs[128 * 64];  // 32 KB
  const float* xb = x + ((size_t)b * TT + t0) * EE + h * 64;
#pragma unroll
  for (int j = 0; j < 8; ++j) {
    int idx4 = j * 256 + r;
    int t = idx4 >> 4, c4 = idx4 & 15;
    *reinterpret_cast<float4*>(&Xs[t * 64 + c4 * 4]) =
        *reinterpret_cast<const float4*>(&xb[(size_t)t * EE + c4 * 4]);
  }
  __syncthreads();
  // bf16 copy for kC
#pragma unroll
  for (int j = 0; j < 4; ++j) {
    int idx8 = j * 256 + r;           // 1024 chunks of 8
    int t = idx8 >> 3, gch = idx8 & 7;
    ushort8v o;
#pragma unroll
    for (int e = 0; e < 8; ++e) o[e] = f2bf(Xs[t * 64 + gch * 8 + e]);
    *reinterpret_cast<ushort8v*>(&xbf[((size_t)bh * TT + t0 + t) * 64 + gch * 8]) = o;
  }
  const int p0 = (r >> 4) * 4, q0 = (r & 15) * 4;
  float acc[4][4] = {};
  for (int t = 0; t < 128; ++t) {
    float4 pv = *reinterpret_cast<const float4*>(&Xs[t * 64 + p0]);
    float4 qv = *reinterpret_cast<const float4*>(&Xs[t * 64 + q0]);
    float pa[4] = {pv.x, pv.y, pv.z, pv.w};
    float qa[4] = {qv.x, qv.y, qv.z, qv.w};
#pragma unroll
    for (int i = 0; i < 4; ++i)
#pragma unroll
      for (int j = 0; j < 4; ++j) acc[i][j] += pa[i] * qa[j];
  }
  float* Sb = Sxx + bh * 4096;
#pragma unroll
  for (int i = 0; i < 4; ++i)
#pragma unroll
    for (int j = 0; j < 4; ++j)
      atomicAdd(&Sb[(p0 + i) * 64 + q0 + j], acc[i][j]);
  if (r < 64) {
    float s = 0.f;
    for (int t = 0; t < 128; ++t) s += Xs[t * 64 + r];
    atomicAdd(&sx[bh * 64 + r], s);
  }
}

// ---------------------------------------------------------------------------
// Kernel B1: per (b,h,i): scores -> softmax -> M = w @ Wv, c = w @ bv.
// Emits Mt (bf16) rows n = bh*64+d, cols e = i*64+p  (transposed for kB2's
// B-operand), and c as bf16 into Mt row 2048+bh.
// grid 512 (bh*16+i), block 256.
// ---------------------------------------------------------------------------
__global__ __launch_bounds__(256) void kB1(const float* __restrict__ Sxx,
                                           const float* __restrict__ sx,
                                           const float* __restrict__ Wq,
                                           const float* __restrict__ bq,
                                           const float* __restrict__ Wk,
                                           const float* __restrict__ bk,
                                           const float* __restrict__ Wv,
                                           const float* __restrict__ bv,
                                           unsigned short* __restrict__ Mtbf) {
  const int blk = blockIdx.x;
  const int bh = blk >> 4, ih = blk & 15;
  const int r = threadIdx.x;
  __shared__ float Ss[64 * 65];   // S_xx, later scores/w
  __shared__ float Ws[64 * 65];   // Wq -> Wk -> Wv
  __shared__ float A1[64 * 65];   // Wq @ S_xx, later M^T
  __shared__ float svec[64], qs[64], ks[64], bqv[64], bkv[64], bvv[64];

#pragma unroll
  for (int j = 0; j < 16; ++j) {
    int idx = j * 256 + r;
    int row = idx >> 6, col = idx & 63;
    Ss[row * 65 + col] = Sxx[bh * 4096 + idx];
    Ws[row * 65 + col] = Wq[ih * 4096 + idx];
  }
  if (r < 64) {
    svec[r] = sx[bh * 64 + r];
    bqv[r] = bq[ih * 64 + r];
    bkv[r] = bk[ih * 64 + r];
    bvv[r] = bv[ih * 64 + r];
  }
  __syncthreads();
  const int p0 = (r >> 4) * 4, q0 = (r & 15) * 4;
  // A1 = Wq @ S
  {
    float acc[4][4] = {};
    for (int d = 0; d < 64; ++d) {
      float wv[4], sv[4];
#pragma unroll
      for (int i = 0; i < 4; ++i) wv[i] = Ws[(p0 + i) * 65 + d];
#pragma unroll
      for (int j = 0; j < 4; ++j) sv[j] = Ss[d * 65 + q0 + j];
#pragma unroll
      for (int i = 0; i < 4; ++i)
#pragma unroll
        for (int j = 0; j < 4; ++j) acc[i][j] += wv[i] * sv[j];
    }
#pragma unroll
    for (int i = 0; i < 4; ++i)
#pragma unroll
      for (int j = 0; j < 4; ++j) A1[(p0 + i) * 65 + q0 + j] = acc[i][j];
  }
  if (r < 64) {  // qs = Wq @ s_x
    float s = 0.f;
    for (int d = 0; d < 64; ++d) s += Ws[r * 65 + d] * svec[d];
    qs[r] = s;
  }
  __syncthreads();
#pragma unroll
  for (int j = 0; j < 16; ++j) {
    int idx = j * 256 + r;
    int row = idx >> 6, col = idx & 63;
    Ws[row * 65 + col] = Wk[ih * 4096 + idx];
  }
  __syncthreads();
  if (r < 64) {  // ks = Wk @ s_x
    float s = 0.f;
    for (int d = 0; d < 64; ++d) s += Ws[r * 65 + d] * svec[d];
    ks[r] = s;
  }
  __syncthreads();
  // scores
  {
    float acc[4][4] = {};
    for (int d = 0; d < 64; ++d) {
      float av[4], kv[4];
#pragma unroll
      for (int i = 0; i < 4; ++i) av[i] = A1[(p0 + i) * 65 + d];
#pragma unroll
      for (int j = 0; j < 4; ++j) kv[j] = Ws[(q0 + j) * 65 + d];
#pragma unroll
      for (int i = 0; i < 4; ++i)
#pragma unroll
        for (int j = 0; j < 4; ++j) acc[i][j] += av[i] * kv[j];
    }
#pragma unroll
    for (int i = 0; i < 4; ++i)
#pragma unroll
      for (int j = 0; j < 4; ++j) {
        float v = acc[i][j] + qs[p0 + i] * bkv[q0 + j] + bqv[p0 + i] * ks[q0 + j] +
                  1024.f * bqv[p0 + i] * bkv[q0 + j];
        Ss[(p0 + i) * 65 + q0 + j] = v * 0.125f;
      }
  }
  __syncthreads();
  if (r < 64) {  // softmax row
    float* row = &Ss[r * 65];
    float m = row[0];
    for (int q = 1; q < 64; ++q) m = fmaxf(m, row[q]);
    float s = 0.f;
    for (int q = 0; q < 64; ++q) {
      float e = __expf(row[q] - m);
      row[q] = e;
      s += e;
    }
    float inv = 1.f / s;
    for (int q = 0; q < 64; ++q) row[q] *= inv;
  }
  __syncthreads();
#pragma unroll
  for (int j = 0; j < 16; ++j) {
    int idx = j * 256 + r;
    int row = idx >> 6, col = idx & 63;
    Ws[row * 65 + col] = Wv[ih * 4096 + idx];
  }
  __syncthreads();
  // M[p][d] = sum_q w[p][q] Wv[q][d]; store M^T into A1
  {
    const int d0 = q0;
    float acc[4][4] = {};
    for (int q = 0; q < 64; ++q) {
      float wv[4], vv[4];
#pragma unroll
      for (int i = 0; i < 4; ++i) wv[i] = Ss[(p0 + i) * 65 + q];
#pragma unroll
      for (int j = 0; j < 4; ++j) vv[j] = Ws[q * 65 + d0 + j];
#pragma unroll
      for (int i = 0; i < 4; ++i)
#pragma unroll
        for (int j = 0; j < 4; ++j) acc[i][j] += wv[i] * vv[j];
    }
#pragma unroll
    for (int i = 0; i < 4; ++i)
#pragma unroll
      for (int j = 0; j < 4; ++j) A1[(d0 + j) * 65 + (p0 + i)] = acc[i][j];
  }
  if (r < 64) {  // c[e = ih*64 + r] -> bf16 row 2048+bh of Mt
    float s = 0.f;
    for (int q = 0; q < 64; ++q) s += Ss[r * 65 + q] * bvv[q];
    Mtbf[(size_t)(2048 + bh) * 1024 + ih * 64 + r] = f2bf(s);
  }
  __syncthreads();
  // write Mt[bh*64+d][ih*64 + p] from A1 (bf16, coalesced 32B/thread)
  {
    const int d = r >> 2, pg = (r & 3) * 16;
    ushort8v o0, o1;
#pragma unroll
    for (int j = 0; j < 8; ++j) o0[j] = f2bf(A1[d * 65 + pg + j]);
#pragma unroll
    for (int j = 0; j < 8; ++j) o1[j] = f2bf(A1[d * 65 + pg + 8 + j]);
    unsigned short* dst = Mtbf + (size_t)(bh * 64 + d) * 1024 + ih * 64 + pg;
    *reinterpret_cast<ushort8v*>(dst) = o0;
    *reinterpret_cast<ushort8v*>(dst + 8) = o1;
  }
}

// ---------------------------------------------------------------------------
// Kernel B2 (MFMA, LDS-free): D[f][n] = sum_e Wfbf[f][e] * Mt[n][e]
// n = bh*64+d  (n<2048): G; n = 2048+bh (tile 32): g = Wf@c + bf.
// grid (8, 33): f-tile 128, n-tile 64. block 256 = 4 waves (2x2).
// ---------------------------------------------------------------------------
__global__ __launch_bounds__(256) void kB2(const unsigned short* __restrict__ Wfbf,
                                           const unsigned short* __restrict__ Mtbf,
                                           const float* __restrict__ bfv,
                                           unsigned short* __restrict__ Gbf,
                                           float* __restrict__ g) {
  const int fx = blockIdx.x, ny = blockIdx.y;
  const int r = threadIdx.x;
  const int w = r >> 6, l = r & 63;
  const int wr = w >> 1, wc = w & 1;
  const int lm = l & 15, lk = l >> 4;
  const int f_base = fx * 128 + wr * 64;
  const int n_base = ny * 64 + wc * 32;
  const unsigned short* ap = Wfbf + (size_t)(f_base + lm) * 1024 + lk * 8;
  const unsigned short* bp = Mtbf + (size_t)(n_base + lm) * 1024 + lk * 8;
  floatx4 acc[4][2] = {};
  for (int k0 = 0; k0 < 1024; k0 += 64) {
    short8 a[4][2], b[2][2];
#pragma unroll
    for (int mi = 0; mi < 4; ++mi)
#pragma unroll
      for (int ks = 0; ks < 2; ++ks)
        a[mi][ks] = *reinterpret_cast<const short8*>(ap + mi * 16 * 1024 + k0 + ks * 32);
#pragma unroll
    for (int ni = 0; ni < 2; ++ni)
#pragma unroll
      for (int ks = 0; ks < 2; ++ks)
        b[ni][ks] = *reinterpret_cast<const short8*>(bp + ni * 16 * 1024 + k0 + ks * 32);
#pragma unroll
    for (int ks = 0; ks < 2; ++ks)
#pragma unroll
      for (int mi = 0; mi < 4; ++mi)
#pragma unroll
        for (int ni = 0; ni < 2; ++ni)
          acc[mi][ni] = __builtin_amdgcn_mfma_f32_16x16x32_bf16(
              a[mi][ks], b[ni][ks], acc[mi][ni], 0, 0, 0);
  }
  if (ny < 32) {
    const int bh = ny;
#pragma unroll
    for (int mi = 0; mi < 4; ++mi)
#pragma unroll
      for (int ni = 0; ni < 2; ++ni) {
        const int d = wc * 32 + ni * 16 + lm;
        const int fr = f_base + mi * 16 + lk * 4;
#pragma unroll
        for (int q = 0; q < 4; ++q)
          Gbf[(size_t)bh * 65536 + (size_t)(fr + q) * 64 + d] = f2bf(acc[mi][ni][q]);
      }
  } else if (wc == 0) {  // n = 2048 + (ni*16+lm) = 2048 + bh
#pragma unroll
    for (int mi = 0; mi < 4; ++mi)
#pragma unroll
      for (int ni = 0; ni < 2; ++ni) {
        const int bh = ni * 16 + lm;
        const int fr = f_base + mi * 16 + lk * 4;
#pragma unroll
        for (int q = 0; q < 4; ++q)
          g[bh * 1024 + fr + q] = acc[mi][ni][q] + bfv[fr + q];
      }
  }
}

// ---------------------------------------------------------------------------
// Kernel C (MFMA, LDS-free): out[bh][t][f] = sum_d xbf[bh][t][d]*Gbf[bh][f][d]
//                            + g[bh][f]
// grid (64, 32): (t-tile x f-tile of 128x128), bh. block 256 = 4 waves (2x2).
// ---------------------------------------------------------------------------
__global__ __launch_bounds__(256) void kC(const unsigned short* __restrict__ xbf,
                                          const unsigned short* __restrict__ Gbf,
                                          const float* __restrict__ g,
                                          float* __restrict__ out) {
  const int bh = blockIdx.y;
  const int t0 = (blockIdx.x >> 3) * 128, f0 = (blockIdx.x & 7) * 128;
  const int r = threadIdx.x;
  const int w = r >> 6, l = r & 63;
  const int wr = w >> 1, wc = w & 1;
  const int lm = l & 15, lk = l >> 4;
  const unsigned short* ap =
      xbf + (size_t)bh * 65536 + (size_t)(t0 + wr * 64 + lm) * 64 + lk * 8;
  const unsigned short* bp =
      Gbf + (size_t)bh * 65536 + (size_t)(f0 + wc * 64 + lm) * 64 + lk * 8;
  short8 a[4][2], b[4][2];
#pragma unroll
  for (int mi = 0; mi < 4; ++mi)
#pragma unroll
    for (int ks = 0; ks < 2; ++ks)
      a[mi][ks] = *reinterpret_cast<const short8*>(ap + mi * 16 * 64 + ks * 32);
#pragma unroll
  for (int ni = 0; ni < 4; ++ni)
#pragma unroll
    for (int ks = 0; ks < 2; ++ks)
      b[ni][ks] = *reinterpret_cast<const short8*>(bp + ni * 16 * 64 + ks * 32);
  floatx4 acc[4][4] = {};
#pragma unroll
  for (int ks = 0; ks < 2; ++ks)
#pragma unroll
    for (int mi = 0; mi < 4; ++mi)
#pragma unroll
      for (int ni = 0; ni < 4; ++ni)
        acc[mi][ni] = __builtin_amdgcn_mfma_f32_16x16x32_bf16(
            a[mi][ks], b[ni][ks], acc[mi][ni], 0, 0, 0);
  float gv[4];
#pragma unroll
  for (int ni = 0; ni < 4; ++ni)
    gv[ni] = g[bh * 1024 + f0 + wc * 64 + ni * 16 + lm];
  float* ob = out + (size_t)bh * 1048576;
#pragma unroll
  for (int mi = 0; mi < 4; ++mi)
#pragma unroll
    for (int ni = 0; ni < 4; ++ni) {
      const int f = f0 + wc * 64 + ni * 16 + lm;
#pragma unroll
      for (int q = 0; q < 4; ++q) {
        const int t = t0 + wr * 64 + mi * 16 + lk * 4 + q;
        ob[(size_t)t * 1024 + f] = acc[mi][ni][q] + gv[ni];
      }
    }
}

extern "C" void kernel_launch(void* const* d_in, const int* in_sizes, int n_in,
                              void* d_out, int out_size, void* d_ws, size_t ws_size,
                              hipStream_t stream) {
  const float* x = (const float*)d_in[0];
  const float* Wq = (const float*)d_in[1];
  const float* bq = (const float*)d_in[2];
  const float* Wk = (const float*)d_in[3];
  const float* bk = (const float*)d_in[4];
  const float* Wv = (const float*)d_in[5];
  const float* bv = (const float*)d_in[6];
  const float* Wf = (const float*)d_in[7];
  const float* bf = (const float*)d_in[8];
  float* out = (float*)d_out;

  float* ws = (float*)d_ws;
  float* Sxx = ws;                                   // 131072 f
  float* sx = Sxx + 131072;                          // 2048 f
  float* g = sx + 2048;                              // 32768 f
  unsigned short* Wfbf = (unsigned short*)(g + 32768);  // 1048576 us
  unsigned short* xbf = Wfbf + 1048576;              // 2097152 us
  unsigned short* Mtbf = xbf + 2097152;              // 2112*1024 = 2162688 us
  unsigned short* Gbf = Mtbf + 2162688;              // 2097152 us

  hipMemsetAsync(Sxx, 0, 133120 * sizeof(float), stream);
  hipMemsetAsync(Mtbf + (size_t)2080 * 1024, 0, 32 * 1024 * sizeof(unsigned short), stream);
  kW<<<1024, 256, 0, stream>>>(Wf, Wfbf);
  kA<<<dim3(32, 8), 256, 0, stream>>>(x, Sxx, sx, xbf);
  kB1<<<512, 256, 0, stream>>>(Sxx, sx, Wq, bq, Wk, bk, Wv, bv, Mtbf);
  kB2<<<dim3(8, 33), 256, 0, stream>>>(Wfbf, Mtbf, bf, Gbf, g);
  kC<<<dim3(64, 32), 256, 0, stream>>>(xbf, Gbf, g, out);
}

// Round 3
// 123.757 us; speedup vs baseline: 1.8946x; 1.1177x over previous
//
#include <hip/hip_runtime.h>

// Problem constants: B=2, T=1024, E=1024, H=16, D=64
#define BB 2
#define TT 1024
#define EE 1024
#define HH 16
#define DD 64

typedef __attribute__((ext_vector_type(8))) short short8;      // 8 bf16 (4 VGPR) MFMA frag
typedef __attribute__((ext_vector_type(4))) float floatx4;     // MFMA acc
typedef __attribute__((ext_vector_type(4))) unsigned short ushort4v;
typedef __attribute__((ext_vector_type(8))) unsigned short ushort8v;

static __device__ __forceinline__ unsigned short f2bf(float f) {
  union { float f; unsigned int u; } v; v.f = f;
  unsigned int u = v.u;
  u += 0x7FFFu + ((u >> 16) & 1u);  // RNE
  return (unsigned short)(u >> 16);
}

// ---------------------------------------------------------------------------
// kW: Wf (fp32 1024x1024) -> Wfbf (bf16). Also zeroes Sxx+sx (133120 floats)
// with its first 130 blocks — replaces the pathological in-graph memset.
// ---------------------------------------------------------------------------
__global__ __launch_bounds__(256) void kW(const float* __restrict__ Wf,
                                          unsigned short* __restrict__ Wfbf,
                                          float* __restrict__ zero_base) {
  int gid = blockIdx.x * 256 + threadIdx.x;
  int idx = gid * 4;
  float4 v = *reinterpret_cast<const float4*>(&Wf[idx]);
  ushort4v o;
  o[0] = f2bf(v.x); o[1] = f2bf(v.y); o[2] = f2bf(v.z); o[3] = f2bf(v.w);
  *reinterpret_cast<ushort4v*>(&Wfbf[idx]) = o;
  if (gid < 33280)  // 133120 floats = Sxx (131072) + sx (2048)
    *reinterpret_cast<float4*>(&zero_base[idx]) = make_float4(0.f, 0.f, 0.f, 0.f);
}

// ---------------------------------------------------------------------------
// Kernel A: per (b,h): S_xx = sum_t x_t x_t^T, s_x = sum_t x_t (atomic accum)
//           + emit xbf[bh][t][d] (bf16) for kC.
// grid (32, 8): bh, t-chunk of 128. block 256.
// ---------------------------------------------------------------------------
__global__ __launch_bounds__(256) void kA(const float* __restrict__ x,
                                          float* __restrict__ Sxx,
                                          float* __restrict__ sx,
                                          unsigned short* __restrict__ xbf) {
  const int bh = blockIdx.x;
  const int b = bh >> 4, h = bh & 15;
  const int t0 = blockIdx.y * 128;
  const int r = threadIdx.x;
  __shared__ float Xs[128 * 64];  // 32 KB
  const float* xb = x + ((size_t)b * TT + t0) * EE + h * 64;
#pragma unroll
  for (int j = 0; j < 8; ++j) {
    int idx4 = j * 256 + r;
    int t = idx4 >> 4, c4 = idx4 & 15;
    *reinterpret_cast<float4*>(&Xs[t * 64 + c4 * 4]) =
        *reinterpret_cast<const float4*>(&xb[(size_t)t * EE + c4 * 4]);
  }
  __syncthreads();
  // bf16 copy for kC
#pragma unroll
  for (int j = 0; j < 4; ++j) {
    int idx8 = j * 256 + r;           // 1024 chunks of 8
    int t = idx8 >> 3, gch = idx8 & 7;
    ushort8v o;
#pragma unroll
    for (int e = 0; e < 8; ++e) o[e] = f2bf(Xs[t * 64 + gch * 8 + e]);
    *reinterpret_cast<ushort8v*>(&xbf[((size_t)bh * TT + t0 + t) * 64 + gch * 8]) = o;
  }
  const int p0 = (r >> 4) * 4, q0 = (r & 15) * 4;
  float acc[4][4] = {};
  for (int t = 0; t < 128; ++t) {
    float4 pv = *reinterpret_cast<const float4*>(&Xs[t * 64 + p0]);
    float4 qv = *reinterpret_cast<const float4*>(&Xs[t * 64 + q0]);
    float pa[4] = {pv.x, pv.y, pv.z, pv.w};
    float qa[4] = {qv.x, qv.y, qv.z, qv.w};
#pragma unroll
    for (int i = 0; i < 4; ++i)
#pragma unroll
      for (int j = 0; j < 4; ++j) acc[i][j] += pa[i] * qa[j];
  }
  float* Sb = Sxx + bh * 4096;
#pragma unroll
  for (int i = 0; i < 4; ++i)
#pragma unroll
    for (int j = 0; j < 4; ++j)
      atomicAdd(&Sb[(p0 + i) * 64 + q0 + j], acc[i][j]);
  if (r < 64) {
    float s = 0.f;
    for (int t = 0; t < 128; ++t) s += Xs[t * 64 + r];
    atomicAdd(&sx[bh * 64 + r], s);
  }
}

// ---------------------------------------------------------------------------
// Kernel B1: per (b,h,i): scores -> softmax -> M = w @ Wv, c = w @ bv.
// Emits Mt (bf16) rows n = bh*64+d, cols e = i*64+p  (transposed for kB2's
// B-operand), and c as bf16 into Mt row 2048+bh.
// grid 512 (bh*16+i), block 256.
// ---------------------------------------------------------------------------
__global__ __launch_bounds__(256) void kB1(const float* __restrict__ Sxx,
                                           const float* __restrict__ sx,
                                           const float* __restrict__ Wq,
                                           const float* __restrict__ bq,
                                           const float* __restrict__ Wk,
                                           const float* __restrict__ bk,
                                           const float* __restrict__ Wv,
                                           const float* __restrict__ bv,
                                           unsigned short* __restrict__ Mtbf) {
  const int blk = blockIdx.x;
  const int bh = blk >> 4, ih = blk & 15;
  const int r = threadIdx.x;
  __shared__ float Ss[64 * 65];   // S_xx, later scores/w
  __shared__ float Ws[64 * 65];   // Wq -> Wk -> Wv
  __shared__ float A1[64 * 65];   // Wq @ S_xx, later M^T
  __shared__ float svec[64], qs[64], ks[64], bqv[64], bkv[64], bvv[64];

#pragma unroll
  for (int j = 0; j < 16; ++j) {
    int idx = j * 256 + r;
    int row = idx >> 6, col = idx & 63;
    Ss[row * 65 + col] = Sxx[bh * 4096 + idx];
    Ws[row * 65 + col] = Wq[ih * 4096 + idx];
  }
  if (r < 64) {
    svec[r] = sx[bh * 64 + r];
    bqv[r] = bq[ih * 64 + r];
    bkv[r] = bk[ih * 64 + r];
    bvv[r] = bv[ih * 64 + r];
  }
  __syncthreads();
  const int p0 = (r >> 4) * 4, q0 = (r & 15) * 4;
  // A1 = Wq @ S
  {
    float acc[4][4] = {};
    for (int d = 0; d < 64; ++d) {
      float wv[4], sv[4];
#pragma unroll
      for (int i = 0; i < 4; ++i) wv[i] = Ws[(p0 + i) * 65 + d];
#pragma unroll
      for (int j = 0; j < 4; ++j) sv[j] = Ss[d * 65 + q0 + j];
#pragma unroll
      for (int i = 0; i < 4; ++i)
#pragma unroll
        for (int j = 0; j < 4; ++j) acc[i][j] += wv[i] * sv[j];
    }
#pragma unroll
    for (int i = 0; i < 4; ++i)
#pragma unroll
      for (int j = 0; j < 4; ++j) A1[(p0 + i) * 65 + q0 + j] = acc[i][j];
  }
  if (r < 64) {  // qs = Wq @ s_x
    float s = 0.f;
    for (int d = 0; d < 64; ++d) s += Ws[r * 65 + d] * svec[d];
    qs[r] = s;
  }
  __syncthreads();
#pragma unroll
  for (int j = 0; j < 16; ++j) {
    int idx = j * 256 + r;
    int row = idx >> 6, col = idx & 63;
    Ws[row * 65 + col] = Wk[ih * 4096 + idx];
  }
  __syncthreads();
  if (r < 64) {  // ks = Wk @ s_x
    float s = 0.f;
    for (int d = 0; d < 64; ++d) s += Ws[r * 65 + d] * svec[d];
    ks[r] = s;
  }
  __syncthreads();
  // scores
  {
    float acc[4][4] = {};
    for (int d = 0; d < 64; ++d) {
      float av[4], kv[4];
#pragma unroll
      for (int i = 0; i < 4; ++i) av[i] = A1[(p0 + i) * 65 + d];
#pragma unroll
      for (int j = 0; j < 4; ++j) kv[j] = Ws[(q0 + j) * 65 + d];
#pragma unroll
      for (int i = 0; i < 4; ++i)
#pragma unroll
        for (int j = 0; j < 4; ++j) acc[i][j] += av[i] * kv[j];
    }
#pragma unroll
    for (int i = 0; i < 4; ++i)
#pragma unroll
      for (int j = 0; j < 4; ++j) {
        float v = acc[i][j] + qs[p0 + i] * bkv[q0 + j] + bqv[p0 + i] * ks[q0 + j] +
                  1024.f * bqv[p0 + i] * bkv[q0 + j];
        Ss[(p0 + i) * 65 + q0 + j] = v * 0.125f;
      }
  }
  __syncthreads();
  if (r < 64) {  // softmax row
    float* row = &Ss[r * 65];
    float m = row[0];
    for (int q = 1; q < 64; ++q) m = fmaxf(m, row[q]);
    float s = 0.f;
    for (int q = 0; q < 64; ++q) {
      float e = __expf(row[q] - m);
      row[q] = e;
      s += e;
    }
    float inv = 1.f / s;
    for (int q = 0; q < 64; ++q) row[q] *= inv;
  }
  __syncthreads();
#pragma unroll
  for (int j = 0; j < 16; ++j) {
    int idx = j * 256 + r;
    int row = idx >> 6, col = idx & 63;
    Ws[row * 65 + col] = Wv[ih * 4096 + idx];
  }
  __syncthreads();
  // M[p][d] = sum_q w[p][q] Wv[q][d]; store M^T into A1
  {
    const int d0 = q0;
    float acc[4][4] = {};
    for (int q = 0; q < 64; ++q) {
      float wv[4], vv[4];
#pragma unroll
      for (int i = 0; i < 4; ++i) wv[i] = Ss[(p0 + i) * 65 + q];
#pragma unroll
      for (int j = 0; j < 4; ++j) vv[j] = Ws[q * 65 + d0 + j];
#pragma unroll
      for (int i = 0; i < 4; ++i)
#pragma unroll
        for (int j = 0; j < 4; ++j) acc[i][j] += wv[i] * vv[j];
    }
#pragma unroll
    for (int i = 0; i < 4; ++i)
#pragma unroll
      for (int j = 0; j < 4; ++j) A1[(d0 + j) * 65 + (p0 + i)] = acc[i][j];
  }
  if (r < 64) {  // c[e = ih*64 + r] -> bf16 row 2048+bh of Mt
    float s = 0.f;
    for (int q = 0; q < 64; ++q) s += Ss[r * 65 + q] * bvv[q];
    Mtbf[(size_t)(2048 + bh) * 1024 + ih * 64 + r] = f2bf(s);
  }
  __syncthreads();
  // write Mt[bh*64+d][ih*64 + p] from A1 (bf16, coalesced 32B/thread)
  {
    const int d = r >> 2, pg = (r & 3) * 16;
    ushort8v o0, o1;
#pragma unroll
    for (int j = 0; j < 8; ++j) o0[j] = f2bf(A1[d * 65 + pg + j]);
#pragma unroll
    for (int j = 0; j < 8; ++j) o1[j] = f2bf(A1[d * 65 + pg + 8 + j]);
    unsigned short* dst = Mtbf + (size_t)(bh * 64 + d) * 1024 + ih * 64 + pg;
    *reinterpret_cast<ushort8v*>(dst) = o0;
    *reinterpret_cast<ushort8v*>(dst + 8) = o1;
  }
}

// ---------------------------------------------------------------------------
// Kernel B2 (MFMA, LDS-free): D[f][n] = sum_e Wfbf[f][e] * Mt[n][e]
// n = bh*64+d  (n<2048): G; n = 2048+bh (tile 32): g = Wf@c + bf.
// Rows 2080-2111 of Mt are never written: the only waves that would read
// them (ny==32, wc==1) produce no output -> early-return instead of zeroing.
// grid (8, 33): f-tile 128, n-tile 64. block 256 = 4 waves (2x2).
// ---------------------------------------------------------------------------
__global__ __launch_bounds__(256) void kB2(const unsigned short* __restrict__ Wfbf,
                                           const unsigned short* __restrict__ Mtbf,
                                           const float* __restrict__ bfv,
                                           unsigned short* __restrict__ Gbf,
                                           float* __restrict__ g) {
  const int fx = blockIdx.x, ny = blockIdx.y;
  const int r = threadIdx.x;
  const int w = r >> 6, l = r & 63;
  const int wr = w >> 1, wc = w & 1;
  if (ny == 32 && wc == 1) return;  // would read unwritten Mt rows 2080-2111
  const int lm = l & 15, lk = l >> 4;
  const int f_base = fx * 128 + wr * 64;
  const int n_base = ny * 64 + wc * 32;
  const unsigned short* ap = Wfbf + (size_t)(f_base + lm) * 1024 + lk * 8;
  const unsigned short* bp = Mtbf + (size_t)(n_base + lm) * 1024 + lk * 8;
  floatx4 acc[4][2] = {};
  for (int k0 = 0; k0 < 1024; k0 += 64) {
    short8 a[4][2], b[2][2];
#pragma unroll
    for (int mi = 0; mi < 4; ++mi)
#pragma unroll
      for (int ks = 0; ks < 2; ++ks)
        a[mi][ks] = *reinterpret_cast<const short8*>(ap + mi * 16 * 1024 + k0 + ks * 32);
#pragma unroll
    for (int ni = 0; ni < 2; ++ni)
#pragma unroll
      for (int ks = 0; ks < 2; ++ks)
        b[ni][ks] = *reinterpret_cast<const short8*>(bp + ni * 16 * 1024 + k0 + ks * 32);
#pragma unroll
    for (int ks = 0; ks < 2; ++ks)
#pragma unroll
      for (int mi = 0; mi < 4; ++mi)
#pragma unroll
        for (int ni = 0; ni < 2; ++ni)
          acc[mi][ni] = __builtin_amdgcn_mfma_f32_16x16x32_bf16(
              a[mi][ks], b[ni][ks], acc[mi][ni], 0, 0, 0);
  }
  if (ny < 32) {
    const int bh = ny;
#pragma unroll
    for (int mi = 0; mi < 4; ++mi)
#pragma unroll
      for (int ni = 0; ni < 2; ++ni) {
        const int d = wc * 32 + ni * 16 + lm;
        const int fr = f_base + mi * 16 + lk * 4;
#pragma unroll
        for (int q = 0; q < 4; ++q)
          Gbf[(size_t)bh * 65536 + (size_t)(fr + q) * 64 + d] = f2bf(acc[mi][ni][q]);
      }
  } else {  // wc == 0 here; n = 2048 + (ni*16+lm) = 2048 + bh
#pragma unroll
    for (int mi = 0; mi < 4; ++mi)
#pragma unroll
      for (int ni = 0; ni < 2; ++ni) {
        const int bh = ni * 16 + lm;
        const int fr = f_base + mi * 16 + lk * 4;
#pragma unroll
        for (int q = 0; q < 4; ++q)
          g[bh * 1024 + fr + q] = acc[mi][ni][q] + bfv[fr + q];
      }
  }
}

// ---------------------------------------------------------------------------
// Kernel C (MFMA, LDS-free): out[bh][t][f] = sum_d xbf[bh][t][d]*Gbf[bh][f][d]
//                            + g[bh][f]
// grid (64, 32): (t-tile x f-tile of 128x128), bh. block 256 = 4 waves (2x2).
// ---------------------------------------------------------------------------
__global__ __launch_bounds__(256) void kC(const unsigned short* __restrict__ xbf,
                                          const unsigned short* __restrict__ Gbf,
                                          const float* __restrict__ g,
                                          float* __restrict__ out) {
  const int bh = blockIdx.y;
  const int t0 = (blockIdx.x >> 3) * 128, f0 = (blockIdx.x & 7) * 128;
  const int r = threadIdx.x;
  const int w = r >> 6, l = r & 63;
  const int wr = w >> 1, wc = w & 1;
  const int lm = l & 15, lk = l >> 4;
  const unsigned short* ap =
      xbf + (size_t)bh * 65536 + (size_t)(t0 + wr * 64 + lm) * 64 + lk * 8;
  const unsigned short* bp =
      Gbf + (size_t)bh * 65536 + (size_t)(f0 + wc * 64 + lm) * 64 + lk * 8;
  short8 a[4][2], b[4][2];
#pragma unroll
  for (int mi = 0; mi < 4; ++mi)
#pragma unroll
    for (int ks = 0; ks < 2; ++ks)
      a[mi][ks] = *reinterpret_cast<const short8*>(ap + mi * 16 * 64 + ks * 32);
#pragma unroll
  for (int ni = 0; ni < 4; ++ni)
#pragma unroll
    for (int ks = 0; ks < 2; ++ks)
      b[ni][ks] = *reinterpret_cast<const short8*>(bp + ni * 16 * 64 + ks * 32);
  floatx4 acc[4][4] = {};
#pragma unroll
  for (int ks = 0; ks < 2; ++ks)
#pragma unroll
    for (int mi = 0; mi < 4; ++mi)
#pragma unroll
      for (int ni = 0; ni < 4; ++ni)
        acc[mi][ni] = __builtin_amdgcn_mfma_f32_16x16x32_bf16(
            a[mi][ks], b[ni][ks], acc[mi][ni], 0, 0, 0);
  float gv[4];
#pragma unroll
  for (int ni = 0; ni < 4; ++ni)
    gv[ni] = g[bh * 1024 + f0 + wc * 64 + ni * 16 + lm];
  float* ob = out + (size_t)bh * 1048576;
#pragma unroll
  for (int mi = 0; mi < 4; ++mi)
#pragma unroll
    for (int ni = 0; ni < 4; ++ni) {
      const int f = f0 + wc * 64 + ni * 16 + lm;
#pragma unroll
      for (int q = 0; q < 4; ++q) {
        const int t = t0 + wr * 64 + mi * 16 + lk * 4 + q;
        ob[(size_t)t * 1024 + f] = acc[mi][ni][q] + gv[ni];
      }
    }
}

extern "C" void kernel_launch(void* const* d_in, const int* in_sizes, int n_in,
                              void* d_out, int out_size, void* d_ws, size_t ws_size,
                              hipStream_t stream) {
  const float* x = (const float*)d_in[0];
  const float* Wq = (const float*)d_in[1];
  const float* bq = (const float*)d_in[2];
  const float* Wk = (const float*)d_in[3];
  const float* bk = (const float*)d_in[4];
  const float* Wv = (const float*)d_in[5];
  const float* bv = (const float*)d_in[6];
  const float* Wf = (const float*)d_in[7];
  const float* bf = (const float*)d_in[8];
  float* out = (float*)d_out;

  float* ws = (float*)d_ws;
  float* Sxx = ws;                                   // 131072 f
  float* sx = Sxx + 131072;                          // 2048 f
  float* g = sx + 2048;                              // 32768 f
  unsigned short* Wfbf = (unsigned short*)(g + 32768);  // 1048576 us
  unsigned short* xbf = Wfbf + 1048576;              // 2097152 us
  unsigned short* Mtbf = xbf + 2097152;              // 2112*1024 = 2162688 us
  unsigned short* Gbf = Mtbf + 2162688;              // 2097152 us

  kW<<<1024, 256, 0, stream>>>(Wf, Wfbf, Sxx);  // also zeroes Sxx+sx
  kA<<<dim3(32, 8), 256, 0, stream>>>(x, Sxx, sx, xbf);
  kB1<<<512, 256, 0, stream>>>(Sxx, sx, Wq, bq, Wk, bk, Wv, bv, Mtbf);
  kB2<<<dim3(8, 33), 256, 0, stream>>>(Wfbf, Mtbf, bf, Gbf, g);
  kC<<<dim3(64, 32), 256, 0, stream>>>(xbf, Gbf, g, out);
}

// Round 5
// 109.143 us; speedup vs baseline: 2.1483x; 1.1339x over previous
//
#include <hip/hip_runtime.h>

// Problem constants: B=2, T=1024, E=1024, H=16, D=64
#define BB 2
#define TT 1024
#define EE 1024
#define HH 16
#define DD 64

typedef __attribute__((ext_vector_type(8))) short short8;      // 8 bf16 (4 VGPR) MFMA frag
typedef __attribute__((ext_vector_type(4))) float floatx4;     // MFMA acc
typedef __attribute__((ext_vector_type(4))) unsigned short ushort4v;
typedef __attribute__((ext_vector_type(8))) unsigned short ushort8v;

static __device__ __forceinline__ unsigned short f2bf(float f) {
  union { float f; unsigned int u; } v; v.f = f;
  unsigned int u = v.u;
  u += 0x7FFFu + ((u >> 16) & 1u);  // RNE
  return (unsigned short)(u >> 16);
}
static __device__ __forceinline__ float bf2f(unsigned short u) {
  union { unsigned int i; float f; } v; v.i = ((unsigned int)u) << 16;
  return v.f;
}
static __device__ __forceinline__ void splitbf(float x, unsigned short& h,
                                               unsigned short& l) {
  h = f2bf(x);
  l = f2bf(x - bf2f(h));
}
// swizzled LDS access into a 64x64 bf16 tile (128 B rows), XOR bits 4-6 by row&7
static __device__ __forceinline__ unsigned short* lp(const unsigned short* t,
                                                     int row, int byte) {
  return (unsigned short*)((const char*)t + row * 128 + (byte ^ ((row & 7) << 4)));
}
static __device__ __forceinline__ short8 ldf(const unsigned short* t, int row,
                                             int byte) {
  return *(const short8*)((const char*)t + row * 128 + (byte ^ ((row & 7) << 4)));
}

// ---------------------------------------------------------------------------
// kW: Wf (fp32 1024x1024) -> Wfbf (bf16). Also zeroes Sxx+sx (133120 floats).
// ---------------------------------------------------------------------------
__global__ __launch_bounds__(256) void kW(const float* __restrict__ Wf,
                                          unsigned short* __restrict__ Wfbf,
                                          float* __restrict__ zero_base) {
  int gid = blockIdx.x * 256 + threadIdx.x;
  int idx = gid * 4;
  float4 v = *reinterpret_cast<const float4*>(&Wf[idx]);
  ushort4v o;
  o[0] = f2bf(v.x); o[1] = f2bf(v.y); o[2] = f2bf(v.z); o[3] = f2bf(v.w);
  *reinterpret_cast<ushort4v*>(&Wfbf[idx]) = o;
  if (gid < 33280)  // 133120 floats = Sxx (131072) + sx (2048)
    *reinterpret_cast<float4*>(&zero_base[idx]) = make_float4(0.f, 0.f, 0.f, 0.f);
}

// ---------------------------------------------------------------------------
// Kernel A: per (b,h): S_xx = sum_t x_t x_t^T, s_x = sum_t x_t (atomic accum)
//           + emit xbf[bh][t][d] (bf16) for kC.
// ---------------------------------------------------------------------------
__global__ __launch_bounds__(256) void kA(const float* __restrict__ x,
                                          float* __restrict__ Sxx,
                                          float* __restrict__ sx,
                                          unsigned short* __restrict__ xbf) {
  const int bh = blockIdx.x;
  const int b = bh >> 4, h = bh & 15;
  const int t0 = blockIdx.y * 128;
  const int r = threadIdx.x;
  __shared__ float Xs[128 * 64];  // 32 KB
  const float* xb = x + ((size_t)b * TT + t0) * EE + h * 64;
#pragma unroll
  for (int j = 0; j < 8; ++j) {
    int idx4 = j * 256 + r;
    int t = idx4 >> 4, c4 = idx4 & 15;
    *reinterpret_cast<float4*>(&Xs[t * 64 + c4 * 4]) =
        *reinterpret_cast<const float4*>(&xb[(size_t)t * EE + c4 * 4]);
  }
  __syncthreads();
#pragma unroll
  for (int j = 0; j < 4; ++j) {
    int idx8 = j * 256 + r;
    int t = idx8 >> 3, gch = idx8 & 7;
    ushort8v o;
#pragma unroll
    for (int e = 0; e < 8; ++e) o[e] = f2bf(Xs[t * 64 + gch * 8 + e]);
    *reinterpret_cast<ushort8v*>(&xbf[((size_t)bh * TT + t0 + t) * 64 + gch * 8]) = o;
  }
  const int p0 = (r >> 4) * 4, q0 = (r & 15) * 4;
  float acc[4][4] = {};
  for (int t = 0; t < 128; ++t) {
    float4 pv = *reinterpret_cast<const float4*>(&Xs[t * 64 + p0]);
    float4 qv = *reinterpret_cast<const float4*>(&Xs[t * 64 + q0]);
    float pa[4] = {pv.x, pv.y, pv.z, pv.w};
    float qa[4] = {qv.x, qv.y, qv.z, qv.w};
#pragma unroll
    for (int i = 0; i < 4; ++i)
#pragma unroll
      for (int j = 0; j < 4; ++j) acc[i][j] += pa[i] * qa[j];
  }
  float* Sb = Sxx + bh * 4096;
#pragma unroll
  for (int i = 0; i < 4; ++i)
#pragma unroll
    for (int j = 0; j < 4; ++j)
      atomicAdd(&Sb[(p0 + i) * 64 + q0 + j], acc[i][j]);
  if (r < 64) {
    float s = 0.f;
    for (int t = 0; t < 128; ++t) s += Xs[t * 64 + r];
    atomicAdd(&sx[bh * 64 + r], s);
  }
}

// ---------------------------------------------------------------------------
// Kernel B1 (MFMA): per (b,h,i):
//   A1 = Wq@S (split-bf16, 3x MFMA), scores = A1@Wk^T (split-bf16) + bias
//   -> wave-parallel softmax -> M^T = WvT x w (plain bf16 MFMA)
// Output Mt[bh*64+d][i*64+p] bf16, c row 2048+bh.
// 512 blocks (bh*16+i) x 256 threads (4 waves, 2x2 quadrants of 64x64).
// ---------------------------------------------------------------------------
__global__ __launch_bounds__(256) void kB1(const float* __restrict__ Sxx,
                                           const float* __restrict__ sx,
                                           const float* __restrict__ Wq,
                                           const float* __restrict__ bq,
                                           const float* __restrict__ Wk,
                                           const float* __restrict__ bk,
                                           const float* __restrict__ Wv,
                                           const float* __restrict__ bv,
                                           unsigned short* __restrict__ Mtbf) {
  const int blk = blockIdx.x;
  const int bh = blk >> 4, ih = blk & 15;
  const int r = threadIdx.x;
  const int w = r >> 6, l = r & 63;
  const int wm = w >> 1, wn = w & 1;
  const int lm = l & 15, lk = l >> 4;

  __shared__ unsigned short TSh[4096], TSl[4096];  // S hi/lo -> WvT, w
  __shared__ unsigned short TWh[4096], TWl[4096];  // Wq -> Wk (hi/lo)
  __shared__ unsigned short TAh[4096], TAl[4096];  // A1 hi/lo
  __shared__ float SC[64 * 68];                    // fp32 scores
  __shared__ float svec[64], qsv[64], ksv[64], bqv[64], bkv[64], bvv[64];

  // --- stage S (hi/lo) and Wq (hi/lo), coalesced global float4 reads
#pragma unroll
  for (int it = 0; it < 4; ++it) {
    int idx = it * 1024 + r * 4;
    int row = idx >> 6, c0 = idx & 63;
    float4 vs = *(const float4*)&Sxx[bh * 4096 + idx];
    float4 vw = *(const float4*)&Wq[ih * 4096 + idx];
    float fs[4] = {vs.x, vs.y, vs.z, vs.w};
    float fw[4] = {vw.x, vw.y, vw.z, vw.w};
    ushort4v sh, sl, wh, wl;
#pragma unroll
    for (int j = 0; j < 4; ++j) {
      unsigned short th, tl;
      splitbf(fs[j], th, tl);
      sh[j] = th; sl[j] = tl;
      splitbf(fw[j], th, tl);
      wh[j] = th; wl[j] = tl;
    }
    *(ushort4v*)lp(TSh, row, c0 * 2) = sh;
    *(ushort4v*)lp(TSl, row, c0 * 2) = sl;
    *(ushort4v*)lp(TWh, row, c0 * 2) = wh;
    *(ushort4v*)lp(TWl, row, c0 * 2) = wl;
  }
  if (r < 64) {
    svec[r] = sx[bh * 64 + r];
    bqv[r] = bq[ih * 64 + r];
    bkv[r] = bk[ih * 64 + r];
    bvv[r] = bv[ih * 64 + r];
  }
  __syncthreads();

  // --- phase 1: A1[p][dd] = sum_d Wq[p][d] S[d][dd]  (B-tile = S, symmetric)
  floatx4 a1[2][2] = {};
  {
    short8 Ah[2][2], Al[2][2], Bh[2][2], Bl[2][2];
#pragma unroll
    for (int mt = 0; mt < 2; ++mt)
#pragma unroll
      for (int ks = 0; ks < 2; ++ks) {
        Ah[mt][ks] = ldf(TWh, wm * 32 + mt * 16 + lm, ks * 64 + lk * 16);
        Al[mt][ks] = ldf(TWl, wm * 32 + mt * 16 + lm, ks * 64 + lk * 16);
        Bh[mt][ks] = ldf(TSh, wn * 32 + mt * 16 + lm, ks * 64 + lk * 16);
        Bl[mt][ks] = ldf(TSl, wn * 32 + mt * 16 + lm, ks * 64 + lk * 16);
      }
#pragma unroll
    for (int ks = 0; ks < 2; ++ks)
#pragma unroll
      for (int mt = 0; mt < 2; ++mt)
#pragma unroll
        for (int nt = 0; nt < 2; ++nt) {
          a1[mt][nt] = __builtin_amdgcn_mfma_f32_16x16x32_bf16(Ah[mt][ks], Bh[nt][ks], a1[mt][nt], 0, 0, 0);
          a1[mt][nt] = __builtin_amdgcn_mfma_f32_16x16x32_bf16(Ah[mt][ks], Bl[nt][ks], a1[mt][nt], 0, 0, 0);
          a1[mt][nt] = __builtin_amdgcn_mfma_f32_16x16x32_bf16(Al[mt][ks], Bh[nt][ks], a1[mt][nt], 0, 0, 0);
        }
  }
  // write A1 (split) to TA tiles, layout [p][dd]
#pragma unroll
  for (int mt = 0; mt < 2; ++mt)
#pragma unroll
    for (int nt = 0; nt < 2; ++nt)
#pragma unroll
      for (int q = 0; q < 4; ++q) {
        int p = wm * 32 + mt * 16 + lk * 4 + q;
        int dd = wn * 32 + nt * 16 + lm;
        unsigned short h, lo2;
        splitbf(a1[mt][nt][q], h, lo2);
        *lp(TAh, p, dd * 2) = h;
        *lp(TAl, p, dd * 2) = lo2;
      }
  // qs = Wq @ s_x  (4 lanes per row p)
  {
    int p = r >> 2, dc = (r & 3) * 16;
    float s = 0.f;
#pragma unroll
    for (int j = 0; j < 16; ++j) {
      int d = dc + j;
      s += (bf2f(*lp(TWh, p, d * 2)) + bf2f(*lp(TWl, p, d * 2))) * svec[d];
    }
    s += __shfl_xor(s, 1);
    s += __shfl_xor(s, 2);
    if ((r & 3) == 0) qsv[p] = s;
  }
  __syncthreads();

  // --- stage Wk (hi/lo) into TW; WvT (plain bf16) into TSh
#pragma unroll
  for (int it = 0; it < 4; ++it) {
    int idx = it * 1024 + r * 4;
    int row = idx >> 6, c0 = idx & 63;
    float4 vw = *(const float4*)&Wk[ih * 4096 + idx];
    float fw[4] = {vw.x, vw.y, vw.z, vw.w};
    ushort4v wh, wl;
#pragma unroll
    for (int j = 0; j < 4; ++j) {
      unsigned short th, tl;
      splitbf(fw[j], th, tl);
      wh[j] = th; wl[j] = tl;
    }
    *(ushort4v*)lp(TWh, row, c0 * 2) = wh;
    *(ushort4v*)lp(TWl, row, c0 * 2) = wl;
    float4 vv = *(const float4*)&Wv[ih * 4096 + idx];
    int q = row, d0 = c0;  // WvT[d][q] = Wv[q][d]
    *lp(TSh, d0 + 0, q * 2) = f2bf(vv.x);
    *lp(TSh, d0 + 1, q * 2) = f2bf(vv.y);
    *lp(TSh, d0 + 2, q * 2) = f2bf(vv.z);
    *lp(TSh, d0 + 3, q * 2) = f2bf(vv.w);
  }
  __syncthreads();
  // ks = Wk @ s_x
  {
    int p = r >> 2, dc = (r & 3) * 16;
    float s = 0.f;
#pragma unroll
    for (int j = 0; j < 16; ++j) {
      int d = dc + j;
      s += (bf2f(*lp(TWh, p, d * 2)) + bf2f(*lp(TWl, p, d * 2))) * svec[d];
    }
    s += __shfl_xor(s, 1);
    s += __shfl_xor(s, 2);
    if ((r & 3) == 0) ksv[p] = s;
  }
  // --- phase 2: scores[p][q] = sum_dd A1[p][dd] Wk[q][dd]
  floatx4 a2[2][2] = {};
  {
    short8 Ah[2][2], Al[2][2], Bh[2][2], Bl[2][2];
#pragma unroll
    for (int mt = 0; mt < 2; ++mt)
#pragma unroll
      for (int ks = 0; ks < 2; ++ks) {
        Ah[mt][ks] = ldf(TAh, wm * 32 + mt * 16 + lm, ks * 64 + lk * 16);
        Al[mt][ks] = ldf(TAl, wm * 32 + mt * 16 + lm, ks * 64 + lk * 16);
        Bh[mt][ks] = ldf(TWh, wn * 32 + mt * 16 + lm, ks * 64 + lk * 16);
        Bl[mt][ks] = ldf(TWl, wn * 32 + mt * 16 + lm, ks * 64 + lk * 16);
      }
#pragma unroll
    for (int ks = 0; ks < 2; ++ks)
#pragma unroll
      for (int mt = 0; mt < 2; ++mt)
#pragma unroll
        for (int nt = 0; nt < 2; ++nt) {
          a2[mt][nt] = __builtin_amdgcn_mfma_f32_16x16x32_bf16(Ah[mt][ks], Bh[nt][ks], a2[mt][nt], 0, 0, 0);
          a2[mt][nt] = __builtin_amdgcn_mfma_f32_16x16x32_bf16(Ah[mt][ks], Bl[nt][ks], a2[mt][nt], 0, 0, 0);
          a2[mt][nt] = __builtin_amdgcn_mfma_f32_16x16x32_bf16(Al[mt][ks], Bh[nt][ks], a2[mt][nt], 0, 0, 0);
        }
  }
  __syncthreads();  // ksv visible to all
  // bias + scale -> SC fp32
#pragma unroll
  for (int mt = 0; mt < 2; ++mt)
#pragma unroll
    for (int nt = 0; nt < 2; ++nt)
#pragma unroll
      for (int q = 0; q < 4; ++q) {
        int p = wm * 32 + mt * 16 + lk * 4 + q;
        int qq = wn * 32 + nt * 16 + lm;
        float v = a2[mt][nt][q] + qsv[p] * bkv[qq] + bqv[p] * ksv[qq] +
                  1024.f * bqv[p] * bkv[qq];
        SC[p * 68 + qq] = v * 0.125f;
      }
  __syncthreads();
  // --- wave-parallel softmax (4 lanes/row) -> w bf16 into TSl; c -> global
  {
    int p = r >> 2, qc = (r & 3) * 16;
    float e[16];
    float m = -1e30f;
#pragma unroll
    for (int j = 0; j < 16; ++j) {
      e[j] = SC[p * 68 + qc + j];
      m = fmaxf(m, e[j]);
    }
    m = fmaxf(m, __shfl_xor(m, 1));
    m = fmaxf(m, __shfl_xor(m, 2));
    float s = 0.f, cp = 0.f;
#pragma unroll
    for (int j = 0; j < 16; ++j) {
      float ex = __expf(e[j] - m);
      e[j] = ex;
      s += ex;
      cp += ex * bvv[qc + j];
    }
    s += __shfl_xor(s, 1);
    s += __shfl_xor(s, 2);
    cp += __shfl_xor(cp, 1);
    cp += __shfl_xor(cp, 2);
    float inv = 1.f / s;
#pragma unroll
    for (int j = 0; j < 16; ++j) *lp(TSl, p, (qc + j) * 2) = f2bf(e[j] * inv);
    if ((r & 3) == 0)
      Mtbf[(size_t)(2048 + bh) * 1024 + ih * 64 + p] = f2bf(cp * inv);
  }
  __syncthreads();
  // --- phase 3: M^T[d][p] = sum_q WvT[d][q] w[p][q]  (plain bf16)
  floatx4 a3[2][2] = {};
  {
    short8 A3[2][2], B3[2][2];
#pragma unroll
    for (int mt = 0; mt < 2; ++mt)
#pragma unroll
      for (int ks = 0; ks < 2; ++ks) {
        A3[mt][ks] = ldf(TSh, wm * 32 + mt * 16 + lm, ks * 64 + lk * 16);
        B3[mt][ks] = ldf(TSl, wn * 32 + mt * 16 + lm, ks * 64 + lk * 16);
      }
#pragma unroll
    for (int ks = 0; ks < 2; ++ks)
#pragma unroll
      for (int mt = 0; mt < 2; ++mt)
#pragma unroll
        for (int nt = 0; nt < 2; ++nt)
          a3[mt][nt] = __builtin_amdgcn_mfma_f32_16x16x32_bf16(A3[mt][ks], B3[nt][ks], a3[mt][nt], 0, 0, 0);
  }
#pragma unroll
  for (int mt = 0; mt < 2; ++mt)
#pragma unroll
    for (int nt = 0; nt < 2; ++nt)
#pragma unroll
      for (int q = 0; q < 4; ++q) {
        int d = wm * 32 + mt * 16 + lk * 4 + q;
        int p = wn * 32 + nt * 16 + lm;
        Mtbf[(size_t)(bh * 64 + d) * 1024 + ih * 64 + p] = f2bf(a3[mt][nt][q]);
      }
}

// ---------------------------------------------------------------------------
// Kernel B2 (MFMA, LDS-free): D[f][n] = sum_e Wfbf[f][e] * Mt[n][e]
// n = bh*64+d (n<2048): G; n = 2048+bh (tile 32): g = Wf@c + bf.
// ---------------------------------------------------------------------------
__global__ __launch_bounds__(256) void kB2(const unsigned short* __restrict__ Wfbf,
                                           const unsigned short* __restrict__ Mtbf,
                                           const float* __restrict__ bfv,
                                           unsigned short* __restrict__ Gbf,
                                           float* __restrict__ g) {
  const int fx = blockIdx.x, ny = blockIdx.y;
  const int r = threadIdx.x;
  const int w = r >> 6, l = r & 63;
  const int wr = w >> 1, wc = w & 1;
  if (ny == 32 && wc == 1) return;  // would read unwritten Mt rows 2080-2111
  const int lm = l & 15, lk = l >> 4;
  const int f_base = fx * 128 + wr * 64;
  const int n_base = ny * 64 + wc * 32;
  const unsigned short* ap = Wfbf + (size_t)(f_base + lm) * 1024 + lk * 8;
  const unsigned short* bp = Mtbf + (size_t)(n_base + lm) * 1024 + lk * 8;
  floatx4 acc[4][2] = {};
  for (int k0 = 0; k0 < 1024; k0 += 64) {
    short8 a[4][2], b[2][2];
#pragma unroll
    for (int mi = 0; mi < 4; ++mi)
#pragma unroll
      for (int ks = 0; ks < 2; ++ks)
        a[mi][ks] = *reinterpret_cast<const short8*>(ap + mi * 16 * 1024 + k0 + ks * 32);
#pragma unroll
    for (int ni = 0; ni < 2; ++ni)
#pragma unroll
      for (int ks = 0; ks < 2; ++ks)
        b[ni][ks] = *reinterpret_cast<const short8*>(bp + ni * 16 * 1024 + k0 + ks * 32);
#pragma unroll
    for (int ks = 0; ks < 2; ++ks)
#pragma unroll
      for (int mi = 0; mi < 4; ++mi)
#pragma unroll
        for (int ni = 0; ni < 2; ++ni)
          acc[mi][ni] = __builtin_amdgcn_mfma_f32_16x16x32_bf16(
              a[mi][ks], b[ni][ks], acc[mi][ni], 0, 0, 0);
  }
  if (ny < 32) {
    const int bh = ny;
#pragma unroll
    for (int mi = 0; mi < 4; ++mi)
#pragma unroll
      for (int ni = 0; ni < 2; ++ni) {
        const int d = wc * 32 + ni * 16 + lm;
        const int fr = f_base + mi * 16 + lk * 4;
#pragma unroll
        for (int q = 0; q < 4; ++q)
          Gbf[(size_t)bh * 65536 + (size_t)(fr + q) * 64 + d] = f2bf(acc[mi][ni][q]);
      }
  } else {  // wc == 0; n = 2048 + (ni*16+lm) = 2048 + bh
#pragma unroll
    for (int mi = 0; mi < 4; ++mi)
#pragma unroll
      for (int ni = 0; ni < 2; ++ni) {
        const int bh = ni * 16 + lm;
        const int fr = f_base + mi * 16 + lk * 4;
#pragma unroll
        for (int q = 0; q < 4; ++q)
          g[bh * 1024 + fr + q] = acc[mi][ni][q] + bfv[fr + q];
      }
  }
}

// ---------------------------------------------------------------------------
// Kernel C (MFMA, LDS-free): out[bh][t][f] = sum_d xbf[bh][t][d]*Gbf[bh][f][d]
//                            + g[bh][f]
// ---------------------------------------------------------------------------
__global__ __launch_bounds__(256) void kC(const unsigned short* __restrict__ xbf,
                                          const unsigned short* __restrict__ Gbf,
                                          const float* __restrict__ g,
                                          float* __restrict__ out) {
  const int bh = blockIdx.y;
  const int t0 = (blockIdx.x >> 3) * 128, f0 = (blockIdx.x & 7) * 128;
  const int r = threadIdx.x;
  const int w = r >> 6, l = r & 63;
  const int wr = w >> 1, wc = w & 1;
  const int lm = l & 15, lk = l >> 4;
  const unsigned short* ap =
      xbf + (size_t)bh * 65536 + (size_t)(t0 + wr * 64 + lm) * 64 + lk * 8;
  const unsigned short* bp =
      Gbf + (size_t)bh * 65536 + (size_t)(f0 + wc * 64 + lm) * 64 + lk * 8;
  short8 a[4][2], b[4][2];
#pragma unroll
  for (int mi = 0; mi < 4; ++mi)
#pragma unroll
    for (int ks = 0; ks < 2; ++ks)
      a[mi][ks] = *reinterpret_cast<const short8*>(ap + mi * 16 * 64 + ks * 32);
#pragma unroll
  for (int ni = 0; ni < 4; ++ni)
#pragma unroll
    for (int ks = 0; ks < 2; ++ks)
      b[ni][ks] = *reinterpret_cast<const short8*>(bp + ni * 16 * 64 + ks * 32);
  floatx4 acc[4][4] = {};
#pragma unroll
  for (int ks = 0; ks < 2; ++ks)
#pragma unroll
    for (int mi = 0; mi < 4; ++mi)
#pragma unroll
      for (int ni = 0; ni < 4; ++ni)
        acc[mi][ni] = __builtin_amdgcn_mfma_f32_16x16x32_bf16(
            a[mi][ks], b[ni][ks], acc[mi][ni], 0, 0, 0);
  float gv[4];
#pragma unroll
  for (int ni = 0; ni < 4; ++ni)
    gv[ni] = g[bh * 1024 + f0 + wc * 64 + ni * 16 + lm];
  float* ob = out + (size_t)bh * 1048576;
#pragma unroll
  for (int mi = 0; mi < 4; ++mi)
#pragma unroll
    for (int ni = 0; ni < 4; ++ni) {
      const int f = f0 + wc * 64 + ni * 16 + lm;
#pragma unroll
      for (int q = 0; q < 4; ++q) {
        const int t = t0 + wr * 64 + mi * 16 + lk * 4 + q;
        ob[(size_t)t * 1024 + f] = acc[mi][ni][q] + gv[ni];
      }
    }
}

extern "C" void kernel_launch(void* const* d_in, const int* in_sizes, int n_in,
                              void* d_out, int out_size, void* d_ws, size_t ws_size,
                              hipStream_t stream) {
  const float* x = (const float*)d_in[0];
  const float* Wq = (const float*)d_in[1];
  const float* bq = (const float*)d_in[2];
  const float* Wk = (const float*)d_in[3];
  const float* bk = (const float*)d_in[4];
  const float* Wv = (const float*)d_in[5];
  const float* bv = (const float*)d_in[6];
  const float* Wf = (const float*)d_in[7];
  const float* bf = (const float*)d_in[8];
  float* out = (float*)d_out;

  float* ws = (float*)d_ws;
  float* Sxx = ws;                                   // 131072 f
  float* sx = Sxx + 131072;                          // 2048 f
  float* g = sx + 2048;                              // 32768 f
  unsigned short* Wfbf = (unsigned short*)(g + 32768);  // 1048576 us
  unsigned short* xbf = Wfbf + 1048576;              // 2097152 us
  unsigned short* Mtbf = xbf + 2097152;              // 2112*1024 = 2162688 us
  unsigned short* Gbf = Mtbf + 2162688;              // 2097152 us

  kW<<<1024, 256, 0, stream>>>(Wf, Wfbf, Sxx);  // also zeroes Sxx+sx
  kA<<<dim3(32, 8), 256, 0, stream>>>(x, Sxx, sx, xbf);
  kB1<<<512, 256, 0, stream>>>(Sxx, sx, Wq, bq, Wk, bk, Wv, bv, Mtbf);
  kB2<<<dim3(8, 33), 256, 0, stream>>>(Wfbf, Mtbf, bf, Gbf, g);
  kC<<<dim3(64, 32), 256, 0, stream>>>(xbf, Gbf, g, out);
}

// Round 6
// 99.580 us; speedup vs baseline: 2.3546x; 1.0960x over previous
//
#include <hip/hip_runtime.h>

// Problem constants: B=2, T=1024, E=1024, H=16, D=64
#define BB 2
#define TT 1024
#define EE 1024
#define HH 16
#define DD 64

typedef __attribute__((ext_vector_type(8))) short short8;      // 8 bf16 (4 VGPR) MFMA frag
typedef __attribute__((ext_vector_type(4))) float floatx4;     // MFMA acc
typedef __attribute__((ext_vector_type(4))) unsigned short ushort4v;
typedef __attribute__((ext_vector_type(8))) unsigned short ushort8v;

static __device__ __forceinline__ unsigned short f2bf(float f) {
  union { float f; unsigned int u; } v; v.f = f;
  unsigned int u = v.u;
  u += 0x7FFFu + ((u >> 16) & 1u);  // RNE
  return (unsigned short)(u >> 16);
}
static __device__ __forceinline__ float bf2f(unsigned short u) {
  union { unsigned int i; float f; } v; v.i = ((unsigned int)u) << 16;
  return v.f;
}
static __device__ __forceinline__ void splitbf(float x, unsigned short& h,
                                               unsigned short& l) {
  h = f2bf(x);
  l = f2bf(x - bf2f(h));
}
// swizzled LDS access into a 64x64 bf16 tile (128 B rows), XOR bits 4-6 by row&7
static __device__ __forceinline__ unsigned short* lp(const unsigned short* t,
                                                     int row, int byte) {
  return (unsigned short*)((const char*)t + row * 128 + (byte ^ ((row & 7) << 4)));
}
static __device__ __forceinline__ short8 ldf(const unsigned short* t, int row,
                                             int byte) {
  return *(const short8*)((const char*)t + row * 128 + (byte ^ ((row & 7) << 4)));
}

// ---------------------------------------------------------------------------
// Kernel P (fused prep, 512 blocks):
//  blocks 0-255  : per (bh, t-chunk of 128): Sxx_part / sx_part (NON-atomic,
//                  block-owned slices — no pre-zero needed) + xbf emit.
//  blocks 256-511: Wf fp32 -> bf16 (4096 elements per block).
// ---------------------------------------------------------------------------
__global__ __launch_bounds__(256) void kP(const float* __restrict__ x,
                                          const float* __restrict__ Wf,
                                          float* __restrict__ Sxx_part,
                                          float* __restrict__ sx_part,
                                          unsigned short* __restrict__ Wfbf,
                                          unsigned short* __restrict__ xbf) {
  const int bx = blockIdx.x;
  const int r = threadIdx.x;
  if (bx >= 256) {
    const int wb = bx - 256;
#pragma unroll
    for (int it = 0; it < 4; ++it) {
      int idx = wb * 4096 + it * 1024 + r * 4;
      float4 v = *reinterpret_cast<const float4*>(&Wf[idx]);
      ushort4v o;
      o[0] = f2bf(v.x); o[1] = f2bf(v.y); o[2] = f2bf(v.z); o[3] = f2bf(v.w);
      *reinterpret_cast<ushort4v*>(&Wfbf[idx]) = o;
    }
    return;
  }
  const int bh = bx >> 3, chunk = bx & 7;
  const int b = bh >> 4, h = bh & 15;
  const int t0 = chunk * 128;
  __shared__ float Xs[128 * 64];  // 32 KB
  const float* xb = x + ((size_t)b * TT + t0) * EE + h * 64;
#pragma unroll
  for (int j = 0; j < 8; ++j) {
    int idx4 = j * 256 + r;
    int t = idx4 >> 4, c4 = idx4 & 15;
    *reinterpret_cast<float4*>(&Xs[t * 64 + c4 * 4]) =
        *reinterpret_cast<const float4*>(&xb[(size_t)t * EE + c4 * 4]);
  }
  __syncthreads();
#pragma unroll
  for (int j = 0; j < 4; ++j) {
    int idx8 = j * 256 + r;
    int t = idx8 >> 3, gch = idx8 & 7;
    ushort8v o;
#pragma unroll
    for (int e = 0; e < 8; ++e) o[e] = f2bf(Xs[t * 64 + gch * 8 + e]);
    *reinterpret_cast<ushort8v*>(&xbf[((size_t)bh * TT + t0 + t) * 64 + gch * 8]) = o;
  }
  const int p0 = (r >> 4) * 4, q0 = (r & 15) * 4;
  float acc[4][4] = {};
  for (int t = 0; t < 128; ++t) {
    float4 pv = *reinterpret_cast<const float4*>(&Xs[t * 64 + p0]);
    float4 qv = *reinterpret_cast<const float4*>(&Xs[t * 64 + q0]);
    float pa[4] = {pv.x, pv.y, pv.z, pv.w};
    float qa[4] = {qv.x, qv.y, qv.z, qv.w};
#pragma unroll
    for (int i = 0; i < 4; ++i)
#pragma unroll
      for (int j = 0; j < 4; ++j) acc[i][j] += pa[i] * qa[j];
  }
  float* Sb = Sxx_part + ((size_t)chunk * 32 + bh) * 4096;
#pragma unroll
  for (int i = 0; i < 4; ++i) {
    float4 v = make_float4(acc[i][0], acc[i][1], acc[i][2], acc[i][3]);
    *reinterpret_cast<float4*>(&Sb[(p0 + i) * 64 + q0]) = v;
  }
  if (r < 64) {
    float s = 0.f;
    for (int t = 0; t < 128; ++t) s += Xs[t * 64 + r];
    sx_part[(chunk * 32 + bh) * 64 + r] = s;
  }
}

// ---------------------------------------------------------------------------
// Kernel B1 (MFMA): per (b,h,i):
//   A1 = Wq@S (split-bf16, 3x MFMA), scores = A1@Wk^T (split-bf16) + bias
//   -> wave-parallel softmax -> M^T = WvT x w (plain bf16 MFMA)
// S staged by summing 8 non-atomic partials.
// Output Mt[bh*64+d][i*64+p] bf16, c row 2048+bh.
// ---------------------------------------------------------------------------
__global__ __launch_bounds__(256) void kB1(const float* __restrict__ Sxx_part,
                                           const float* __restrict__ sx_part,
                                           const float* __restrict__ Wq,
                                           const float* __restrict__ bq,
                                           const float* __restrict__ Wk,
                                           const float* __restrict__ bk,
                                           const float* __restrict__ Wv,
                                           const float* __restrict__ bv,
                                           unsigned short* __restrict__ Mtbf) {
  const int blk = blockIdx.x;
  const int bh = blk >> 4, ih = blk & 15;
  const int r = threadIdx.x;
  const int w = r >> 6, l = r & 63;
  const int wm = w >> 1, wn = w & 1;
  const int lm = l & 15, lk = l >> 4;

  __shared__ unsigned short TSh[4096], TSl[4096];  // S hi/lo -> WvT, w
  __shared__ unsigned short TWh[4096], TWl[4096];  // Wq -> Wk (hi/lo)
  __shared__ unsigned short TAh[4096], TAl[4096];  // A1 hi/lo
  __shared__ float SC[64 * 68];                    // fp32 scores
  __shared__ float svec[64], qsv[64], ksv[64], bqv[64], bkv[64], bvv[64];

  // --- stage S (sum of 8 partials, hi/lo) and Wq (hi/lo)
#pragma unroll
  for (int it = 0; it < 4; ++it) {
    int idx = it * 1024 + r * 4;
    int row = idx >> 6, c0 = idx & 63;
    float4 vs = *(const float4*)&Sxx_part[(size_t)bh * 4096 + idx];
#pragma unroll
    for (int ch = 1; ch < 8; ++ch) {
      float4 tv = *(const float4*)&Sxx_part[((size_t)ch * 32 + bh) * 4096 + idx];
      vs.x += tv.x; vs.y += tv.y; vs.z += tv.z; vs.w += tv.w;
    }
    float4 vw = *(const float4*)&Wq[ih * 4096 + idx];
    float fs[4] = {vs.x, vs.y, vs.z, vs.w};
    float fw[4] = {vw.x, vw.y, vw.z, vw.w};
    ushort4v sh, sl, wh, wl;
#pragma unroll
    for (int j = 0; j < 4; ++j) {
      unsigned short th, tl;
      splitbf(fs[j], th, tl);
      sh[j] = th; sl[j] = tl;
      splitbf(fw[j], th, tl);
      wh[j] = th; wl[j] = tl;
    }
    *(ushort4v*)lp(TSh, row, c0 * 2) = sh;
    *(ushort4v*)lp(TSl, row, c0 * 2) = sl;
    *(ushort4v*)lp(TWh, row, c0 * 2) = wh;
    *(ushort4v*)lp(TWl, row, c0 * 2) = wl;
  }
  if (r < 64) {
    float s = 0.f;
#pragma unroll
    for (int ch = 0; ch < 8; ++ch) s += sx_part[(ch * 32 + bh) * 64 + r];
    svec[r] = s;
    bqv[r] = bq[ih * 64 + r];
    bkv[r] = bk[ih * 64 + r];
    bvv[r] = bv[ih * 64 + r];
  }
  __syncthreads();

  // --- phase 1: A1[p][dd] = sum_d Wq[p][d] S[d][dd]  (B-tile = S, symmetric)
  floatx4 a1[2][2] = {};
  {
    short8 Ah[2][2], Al[2][2], Bh[2][2], Bl[2][2];
#pragma unroll
    for (int mt = 0; mt < 2; ++mt)
#pragma unroll
      for (int ks = 0; ks < 2; ++ks) {
        Ah[mt][ks] = ldf(TWh, wm * 32 + mt * 16 + lm, ks * 64 + lk * 16);
        Al[mt][ks] = ldf(TWl, wm * 32 + mt * 16 + lm, ks * 64 + lk * 16);
        Bh[mt][ks] = ldf(TSh, wn * 32 + mt * 16 + lm, ks * 64 + lk * 16);
        Bl[mt][ks] = ldf(TSl, wn * 32 + mt * 16 + lm, ks * 64 + lk * 16);
      }
#pragma unroll
    for (int ks = 0; ks < 2; ++ks)
#pragma unroll
      for (int mt = 0; mt < 2; ++mt)
#pragma unroll
        for (int nt = 0; nt < 2; ++nt) {
          a1[mt][nt] = __builtin_amdgcn_mfma_f32_16x16x32_bf16(Ah[mt][ks], Bh[nt][ks], a1[mt][nt], 0, 0, 0);
          a1[mt][nt] = __builtin_amdgcn_mfma_f32_16x16x32_bf16(Ah[mt][ks], Bl[nt][ks], a1[mt][nt], 0, 0, 0);
          a1[mt][nt] = __builtin_amdgcn_mfma_f32_16x16x32_bf16(Al[mt][ks], Bh[nt][ks], a1[mt][nt], 0, 0, 0);
        }
  }
  // write A1 (split) to TA tiles, layout [p][dd]
#pragma unroll
  for (int mt = 0; mt < 2; ++mt)
#pragma unroll
    for (int nt = 0; nt < 2; ++nt)
#pragma unroll
      for (int q = 0; q < 4; ++q) {
        int p = wm * 32 + mt * 16 + lk * 4 + q;
        int dd = wn * 32 + nt * 16 + lm;
        unsigned short h, lo2;
        splitbf(a1[mt][nt][q], h, lo2);
        *lp(TAh, p, dd * 2) = h;
        *lp(TAl, p, dd * 2) = lo2;
      }
  // qs = Wq @ s_x  (4 lanes per row p)
  {
    int p = r >> 2, dc = (r & 3) * 16;
    float s = 0.f;
#pragma unroll
    for (int j = 0; j < 16; ++j) {
      int d = dc + j;
      s += (bf2f(*lp(TWh, p, d * 2)) + bf2f(*lp(TWl, p, d * 2))) * svec[d];
    }
    s += __shfl_xor(s, 1);
    s += __shfl_xor(s, 2);
    if ((r & 3) == 0) qsv[p] = s;
  }
  __syncthreads();

  // --- stage Wk (hi/lo) into TW; WvT (plain bf16) into TSh
#pragma unroll
  for (int it = 0; it < 4; ++it) {
    int idx = it * 1024 + r * 4;
    int row = idx >> 6, c0 = idx & 63;
    float4 vw = *(const float4*)&Wk[ih * 4096 + idx];
    float fw[4] = {vw.x, vw.y, vw.z, vw.w};
    ushort4v wh, wl;
#pragma unroll
    for (int j = 0; j < 4; ++j) {
      unsigned short th, tl;
      splitbf(fw[j], th, tl);
      wh[j] = th; wl[j] = tl;
    }
    *(ushort4v*)lp(TWh, row, c0 * 2) = wh;
    *(ushort4v*)lp(TWl, row, c0 * 2) = wl;
    float4 vv = *(const float4*)&Wv[ih * 4096 + idx];
    int q = row, d0 = c0;  // WvT[d][q] = Wv[q][d]
    *lp(TSh, d0 + 0, q * 2) = f2bf(vv.x);
    *lp(TSh, d0 + 1, q * 2) = f2bf(vv.y);
    *lp(TSh, d0 + 2, q * 2) = f2bf(vv.z);
    *lp(TSh, d0 + 3, q * 2) = f2bf(vv.w);
  }
  __syncthreads();
  // ks = Wk @ s_x
  {
    int p = r >> 2, dc = (r & 3) * 16;
    float s = 0.f;
#pragma unroll
    for (int j = 0; j < 16; ++j) {
      int d = dc + j;
      s += (bf2f(*lp(TWh, p, d * 2)) + bf2f(*lp(TWl, p, d * 2))) * svec[d];
    }
    s += __shfl_xor(s, 1);
    s += __shfl_xor(s, 2);
    if ((r & 3) == 0) ksv[p] = s;
  }
  // --- phase 2: scores[p][q] = sum_dd A1[p][dd] Wk[q][dd]
  floatx4 a2[2][2] = {};
  {
    short8 Ah[2][2], Al[2][2], Bh[2][2], Bl[2][2];
#pragma unroll
    for (int mt = 0; mt < 2; ++mt)
#pragma unroll
      for (int ks = 0; ks < 2; ++ks) {
        Ah[mt][ks] = ldf(TAh, wm * 32 + mt * 16 + lm, ks * 64 + lk * 16);
        Al[mt][ks] = ldf(TAl, wm * 32 + mt * 16 + lm, ks * 64 + lk * 16);
        Bh[mt][ks] = ldf(TWh, wn * 32 + mt * 16 + lm, ks * 64 + lk * 16);
        Bl[mt][ks] = ldf(TWl, wn * 32 + mt * 16 + lm, ks * 64 + lk * 16);
      }
#pragma unroll
    for (int ks = 0; ks < 2; ++ks)
#pragma unroll
      for (int mt = 0; mt < 2; ++mt)
#pragma unroll
        for (int nt = 0; nt < 2; ++nt) {
          a2[mt][nt] = __builtin_amdgcn_mfma_f32_16x16x32_bf16(Ah[mt][ks], Bh[nt][ks], a2[mt][nt], 0, 0, 0);
          a2[mt][nt] = __builtin_amdgcn_mfma_f32_16x16x32_bf16(Ah[mt][ks], Bl[nt][ks], a2[mt][nt], 0, 0, 0);
          a2[mt][nt] = __builtin_amdgcn_mfma_f32_16x16x32_bf16(Al[mt][ks], Bh[nt][ks], a2[mt][nt], 0, 0, 0);
        }
  }
  __syncthreads();  // ksv visible to all
  // bias + scale -> SC fp32
#pragma unroll
  for (int mt = 0; mt < 2; ++mt)
#pragma unroll
    for (int nt = 0; nt < 2; ++nt)
#pragma unroll
      for (int q = 0; q < 4; ++q) {
        int p = wm * 32 + mt * 16 + lk * 4 + q;
        int qq = wn * 32 + nt * 16 + lm;
        float v = a2[mt][nt][q] + qsv[p] * bkv[qq] + bqv[p] * ksv[qq] +
                  1024.f * bqv[p] * bkv[qq];
        SC[p * 68 + qq] = v * 0.125f;
      }
  __syncthreads();
  // --- wave-parallel softmax (4 lanes/row) -> w bf16 into TSl; c -> global
  {
    int p = r >> 2, qc = (r & 3) * 16;
    float e[16];
    float m = -1e30f;
#pragma unroll
    for (int j = 0; j < 16; ++j) {
      e[j] = SC[p * 68 + qc + j];
      m = fmaxf(m, e[j]);
    }
    m = fmaxf(m, __shfl_xor(m, 1));
    m = fmaxf(m, __shfl_xor(m, 2));
    float s = 0.f, cp = 0.f;
#pragma unroll
    for (int j = 0; j < 16; ++j) {
      float ex = __expf(e[j] - m);
      e[j] = ex;
      s += ex;
      cp += ex * bvv[qc + j];
    }
    s += __shfl_xor(s, 1);
    s += __shfl_xor(s, 2);
    cp += __shfl_xor(cp, 1);
    cp += __shfl_xor(cp, 2);
    float inv = 1.f / s;
#pragma unroll
    for (int j = 0; j < 16; ++j) *lp(TSl, p, (qc + j) * 2) = f2bf(e[j] * inv);
    if ((r & 3) == 0)
      Mtbf[(size_t)(2048 + bh) * 1024 + ih * 64 + p] = f2bf(cp * inv);
  }
  __syncthreads();
  // --- phase 3: M^T[d][p] = sum_q WvT[d][q] w[p][q]  (plain bf16)
  floatx4 a3[2][2] = {};
  {
    short8 A3[2][2], B3[2][2];
#pragma unroll
    for (int mt = 0; mt < 2; ++mt)
#pragma unroll
      for (int ks = 0; ks < 2; ++ks) {
        A3[mt][ks] = ldf(TSh, wm * 32 + mt * 16 + lm, ks * 64 + lk * 16);
        B3[mt][ks] = ldf(TSl, wn * 32 + mt * 16 + lm, ks * 64 + lk * 16);
      }
#pragma unroll
    for (int ks = 0; ks < 2; ++ks)
#pragma unroll
      for (int mt = 0; mt < 2; ++mt)
#pragma unroll
        for (int nt = 0; nt < 2; ++nt)
          a3[mt][nt] = __builtin_amdgcn_mfma_f32_16x16x32_bf16(A3[mt][ks], B3[nt][ks], a3[mt][nt], 0, 0, 0);
  }
#pragma unroll
  for (int mt = 0; mt < 2; ++mt)
#pragma unroll
    for (int nt = 0; nt < 2; ++nt)
#pragma unroll
      for (int q = 0; q < 4; ++q) {
        int d = wm * 32 + mt * 16 + lk * 4 + q;
        int p = wn * 32 + nt * 16 + lm;
        Mtbf[(size_t)(bh * 64 + d) * 1024 + ih * 64 + p] = f2bf(a3[mt][nt][q]);
      }
}

// ---------------------------------------------------------------------------
// Kernel B2 (MFMA, LDS-free): D[f][n] = sum_e Wfbf[f][e] * Mt[n][e]
// 64x64 tiles (4 waves, 2x2 quadrants of 32x32) -> 528 blocks for even CU
// spread. n = bh*64+d (ny<32): G; ny==32: g = Wf@c + bf.
// ---------------------------------------------------------------------------
__global__ __launch_bounds__(256) void kB2(const unsigned short* __restrict__ Wfbf,
                                           const unsigned short* __restrict__ Mtbf,
                                           const float* __restrict__ bfv,
                                           unsigned short* __restrict__ Gbf,
                                           float* __restrict__ g) {
  const int fx = blockIdx.x, ny = blockIdx.y;
  const int r = threadIdx.x;
  const int w = r >> 6, l = r & 63;
  const int wr = w >> 1, wc = w & 1;
  if (ny == 32 && wc == 1) return;  // would read unwritten Mt rows 2080-2111
  const int lm = l & 15, lk = l >> 4;
  const int f_base = fx * 64 + wr * 32;
  const int n_base = ny * 64 + wc * 32;
  const unsigned short* ap = Wfbf + (size_t)(f_base + lm) * 1024 + lk * 8;
  const unsigned short* bp = Mtbf + (size_t)(n_base + lm) * 1024 + lk * 8;
  floatx4 acc[2][2] = {};
  for (int k0 = 0; k0 < 1024; k0 += 64) {
    short8 a[2][2], b[2][2];
#pragma unroll
    for (int mi = 0; mi < 2; ++mi)
#pragma unroll
      for (int ks = 0; ks < 2; ++ks)
        a[mi][ks] = *reinterpret_cast<const short8*>(ap + mi * 16 * 1024 + k0 + ks * 32);
#pragma unroll
    for (int ni = 0; ni < 2; ++ni)
#pragma unroll
      for (int ks = 0; ks < 2; ++ks)
        b[ni][ks] = *reinterpret_cast<const short8*>(bp + ni * 16 * 1024 + k0 + ks * 32);
#pragma unroll
    for (int ks = 0; ks < 2; ++ks)
#pragma unroll
      for (int mi = 0; mi < 2; ++mi)
#pragma unroll
        for (int ni = 0; ni < 2; ++ni)
          acc[mi][ni] = __builtin_amdgcn_mfma_f32_16x16x32_bf16(
              a[mi][ks], b[ni][ks], acc[mi][ni], 0, 0, 0);
  }
  if (ny < 32) {
    const int bh = ny;
#pragma unroll
    for (int mi = 0; mi < 2; ++mi)
#pragma unroll
      for (int ni = 0; ni < 2; ++ni) {
        const int d = wc * 32 + ni * 16 + lm;
        const int fr = f_base + mi * 16 + lk * 4;
#pragma unroll
        for (int q = 0; q < 4; ++q)
          Gbf[(size_t)bh * 65536 + (size_t)(fr + q) * 64 + d] = f2bf(acc[mi][ni][q]);
      }
  } else {  // wc == 0; n = 2048 + (ni*16+lm) = 2048 + bh
#pragma unroll
    for (int mi = 0; mi < 2; ++mi)
#pragma unroll
      for (int ni = 0; ni < 2; ++ni) {
        const int bh = ni * 16 + lm;
        const int fr = f_base + mi * 16 + lk * 4;
#pragma unroll
        for (int q = 0; q < 4; ++q)
          g[bh * 1024 + fr + q] = acc[mi][ni][q] + bfv[fr + q];
      }
  }
}

// ---------------------------------------------------------------------------
// Kernel C (MFMA, LDS-free): out[bh][t][f] = sum_d xbf[bh][t][d]*Gbf[bh][f][d]
//                            + g[bh][f]
// ---------------------------------------------------------------------------
__global__ __launch_bounds__(256) void kC(const unsigned short* __restrict__ xbf,
                                          const unsigned short* __restrict__ Gbf,
                                          const float* __restrict__ g,
                                          float* __restrict__ out) {
  const int bh = blockIdx.y;
  const int t0 = (blockIdx.x >> 3) * 128, f0 = (blockIdx.x & 7) * 128;
  const int r = threadIdx.x;
  const int w = r >> 6, l = r & 63;
  const int wr = w >> 1, wc = w & 1;
  const int lm = l & 15, lk = l >> 4;
  const unsigned short* ap =
      xbf + (size_t)bh * 65536 + (size_t)(t0 + wr * 64 + lm) * 64 + lk * 8;
  const unsigned short* bp =
      Gbf + (size_t)bh * 65536 + (size_t)(f0 + wc * 64 + lm) * 64 + lk * 8;
  short8 a[4][2], b[4][2];
#pragma unroll
  for (int mi = 0; mi < 4; ++mi)
#pragma unroll
    for (int ks = 0; ks < 2; ++ks)
      a[mi][ks] = *reinterpret_cast<const short8*>(ap + mi * 16 * 64 + ks * 32);
#pragma unroll
  for (int ni = 0; ni < 4; ++ni)
#pragma unroll
    for (int ks = 0; ks < 2; ++ks)
      b[ni][ks] = *reinterpret_cast<const short8*>(bp + ni * 16 * 64 + ks * 32);
  floatx4 acc[4][4] = {};
#pragma unroll
  for (int ks = 0; ks < 2; ++ks)
#pragma unroll
    for (int mi = 0; mi < 4; ++mi)
#pragma unroll
      for (int ni = 0; ni < 4; ++ni)
        acc[mi][ni] = __builtin_amdgcn_mfma_f32_16x16x32_bf16(
            a[mi][ks], b[ni][ks], acc[mi][ni], 0, 0, 0);
  float gv[4];
#pragma unroll
  for (int ni = 0; ni < 4; ++ni)
    gv[ni] = g[bh * 1024 + f0 + wc * 64 + ni * 16 + lm];
  float* ob = out + (size_t)bh * 1048576;
#pragma unroll
  for (int mi = 0; mi < 4; ++mi)
#pragma unroll
    for (int ni = 0; ni < 4; ++ni) {
      const int f = f0 + wc * 64 + ni * 16 + lm;
#pragma unroll
      for (int q = 0; q < 4; ++q) {
        const int t = t0 + wr * 64 + mi * 16 + lk * 4 + q;
        ob[(size_t)t * 1024 + f] = acc[mi][ni][q] + gv[ni];
      }
    }
}

extern "C" void kernel_launch(void* const* d_in, const int* in_sizes, int n_in,
                              void* d_out, int out_size, void* d_ws, size_t ws_size,
                              hipStream_t stream) {
  const float* x = (const float*)d_in[0];
  const float* Wq = (const float*)d_in[1];
  const float* bq = (const float*)d_in[2];
  const float* Wk = (const float*)d_in[3];
  const float* bk = (const float*)d_in[4];
  const float* Wv = (const float*)d_in[5];
  const float* bv = (const float*)d_in[6];
  const float* Wf = (const float*)d_in[7];
  const float* bf = (const float*)d_in[8];
  float* out = (float*)d_out;

  float* ws = (float*)d_ws;
  float* Sxx_part = ws;                               // 8*32*4096 = 1048576 f
  float* sx_part = Sxx_part + 1048576;                // 8*32*64   = 16384 f
  float* g = sx_part + 16384;                         // 32768 f
  unsigned short* Wfbf = (unsigned short*)(g + 32768);  // 1048576 us
  unsigned short* xbf = Wfbf + 1048576;               // 2097152 us
  unsigned short* Mtbf = xbf + 2097152;               // 2112*1024 = 2162688 us
  unsigned short* Gbf = Mtbf + 2162688;               // 2097152 us

  kP<<<512, 256, 0, stream>>>(x, Wf, Sxx_part, sx_part, Wfbf, xbf);
  kB1<<<512, 256, 0, stream>>>(Sxx_part, sx_part, Wq, bq, Wk, bk, Wv, bv, Mtbf);
  kB2<<<dim3(16, 33), 256, 0, stream>>>(Wfbf, Mtbf, bf, Gbf, g);
  kC<<<dim3(64, 32), 256, 0, stream>>>(xbf, Gbf, g, out);
}